// Round 4
// baseline (583.884 us; speedup 1.0000x reference)
//
#include <hip/hip_runtime.h>

typedef unsigned int u32;
typedef unsigned short u16;
typedef __bf16 bf16x8 __attribute__((ext_vector_type(8)));
typedef float f32x4 __attribute__((ext_vector_type(4)));

#define B_ 4
#define T_ 1024
#define C_ 1024
#define NH_ 16
#define L_ 512
#define DHR_ 64
#define FF_ 4096

typedef __attribute__((address_space(3))) u32 as3_u32;
typedef __attribute__((address_space(1))) u32 as1_u32;

__device__ __forceinline__ void gld16(const u16* g, u16* l) {
  __builtin_amdgcn_global_load_lds((const as1_u32*)g, (as3_u32*)l, 16, 0, 0);
}

__device__ __forceinline__ float bf2f(u16 u) {
  union { u32 i; float f; } v; v.i = ((u32)u) << 16; return v.f;
}
__device__ __forceinline__ u16 f2bf(float f) {
  union { float f; u32 i; } v; v.f = f;
  u32 r = (v.i + 0x7FFFu + ((v.i >> 16) & 1u)) >> 16;
  return (u16)r;
}

// ---------------------------------------------------------------------------
// Weight transpose + f32->bf16 convert: in f32 [R,C] -> out bf16 [C,R]
// ---------------------------------------------------------------------------
__global__ void transpose_kernel(const float* __restrict__ in, u16* __restrict__ outp,
                                 int R, int C) {
  __shared__ float tile[32][33];
  int bx = blockIdx.x * 32;
  int by = blockIdx.y * 32;
  int tx = threadIdx.x, ty = threadIdx.y;
  for (int i = ty; i < 32; i += 8)
    tile[i][tx] = in[(size_t)(by + i) * C + bx + tx];
  __syncthreads();
  for (int i = ty; i < 32; i += 8)
    outp[(size_t)(bx + i) * R + by + tx] = f2bf(tile[tx][i]);
}

// ---------------------------------------------------------------------------
// RMSNorm: row-per-block, C=1024, f32 in, f32 weight, bf16 out
// ---------------------------------------------------------------------------
__global__ __launch_bounds__(256) void rmsnorm_kernel(const float* __restrict__ xin,
                                                      const float* __restrict__ w,
                                                      u16* __restrict__ outp) {
  const int row = blockIdx.x;
  const int tid = threadIdx.x;
  const float* xp = xin + (size_t)row * C_;
  float v[4];
#pragma unroll
  for (int i = 0; i < 4; i++) v[i] = xp[tid + 256 * i];
  float ss = v[0] * v[0] + v[1] * v[1] + v[2] * v[2] + v[3] * v[3];
#pragma unroll
  for (int o = 32; o > 0; o >>= 1) ss += __shfl_down(ss, o, 64);
  __shared__ float red[4];
  if ((tid & 63) == 0) red[tid >> 6] = ss;
  __syncthreads();
  ss = red[0] + red[1] + red[2] + red[3];
  float scale = rsqrtf(ss * (1.0f / 1024.0f) + 1e-6f);
  u16* op = outp + (size_t)row * C_;
#pragma unroll
  for (int i = 0; i < 4; i++)
    op[tid + 256 * i] = f2bf(v[i] * scale * w[tid + 256 * i]);
}

// ---------------------------------------------------------------------------
// m97-structure MFMA GEMM: 128x128 tile, BK=32, global_load_lds width=16.
// C[M,N] = A[M,K] @ B^T (BT is [N,K] row-major), +bias, +epilogue.
// 256 thr = 4 waves in 2x2; wave computes 64x64 via 4x4 grid of 16x16x32.
// LDS unpadded (global_load_lds requires lane-contiguous dest).
// EPI: 0 bf16 out | 1 f32 out | 2 bf16 out + gelu | 3 f32 out + f32 resid
// ---------------------------------------------------------------------------
template<int EPI>
__global__ __launch_bounds__(256) void gemm128(
    const u16* __restrict__ A, int lda, int aoff,
    const u16* __restrict__ BT, const float* __restrict__ bias,
    const float* __restrict__ resid, void* __restrict__ out,
    int M, int N, int K) {
  __shared__ __align__(16) u16 As[128 * 32];
  __shared__ __align__(16) u16 Bs[128 * 32];
  const int tid = threadIdx.x;
  const int wave = tid >> 6, lane = tid & 63;
  const int wm = wave >> 1, wn = wave & 1;
  const int quad = lane >> 4, l15 = lane & 15;
  const int m0 = blockIdx.x * 128, n0 = blockIdx.y * 128;
  const int row = tid >> 2, seg = tid & 3;  // staging: row 0..63, 16B segment

  const u16* aP = A + (size_t)(m0 + row) * lda + aoff + seg * 8;
  const u16* bP = BT + (size_t)(n0 + row) * K + seg * 8;
  u16* aL = As + row * 32 + seg * 8;
  u16* bL = Bs + row * 32 + seg * 8;
  const size_t aStep = (size_t)64 * lda;
  const size_t bStep = (size_t)64 * K;

  f32x4 acc[4][4] = {};

  for (int k0 = 0; k0 < K; k0 += 32) {
    gld16(aP + k0, aL);
    gld16(aP + k0 + aStep, aL + 64 * 32);
    gld16(bP + k0, bL);
    gld16(bP + k0 + bStep, bL + 64 * 32);
    __syncthreads();  // compiler emits vmcnt(0) drain before barrier
    bf16x8 af[4], bf[4];
#pragma unroll
    for (int mt = 0; mt < 4; mt++)
      af[mt] = *(const bf16x8*)&As[(wm * 64 + mt * 16 + l15) * 32 + quad * 8];
#pragma unroll
    for (int nt = 0; nt < 4; nt++)
      bf[nt] = *(const bf16x8*)&Bs[(wn * 64 + nt * 16 + l15) * 32 + quad * 8];
#pragma unroll
    for (int mt = 0; mt < 4; mt++)
#pragma unroll
      for (int nt = 0; nt < 4; nt++)
        acc[mt][nt] = __builtin_amdgcn_mfma_f32_16x16x32_bf16(af[mt], bf[nt], acc[mt][nt], 0, 0, 0);
    __syncthreads();  // all reads done before next iter's loads land
  }

  // C/D layout: col = l15 (B's n), row = quad*4 + i (A's m)
#pragma unroll
  for (int nt = 0; nt < 4; nt++) {
    const int gn = n0 + wn * 64 + nt * 16 + l15;
    const float bvv = bias[gn];
#pragma unroll
    for (int mt = 0; mt < 4; mt++) {
#pragma unroll
      for (int i = 0; i < 4; i++) {
        const int gm = m0 + wm * 64 + mt * 16 + quad * 4 + i;
        const size_t oidx = (size_t)gm * N + gn;
        float v = acc[mt][nt][i] + bvv;
        if (EPI == 2) {
          float x = v;
          v = 0.5f * x * (1.0f + tanhf(0.7978845608028654f * (x + 0.044715f * x * x * x)));
        }
        if (EPI == 3) v += resid[oidx];
        if (EPI == 1 || EPI == 3) ((float*)out)[oidx] = v;
        else ((u16*)out)[oidx] = f2bf(v);
      }
    }
  }
}

// ---------------------------------------------------------------------------
// Legacy 64x64 GEMM (kept for the N=64 kr matmul only)
// ---------------------------------------------------------------------------
#define SA 40
template<int EPI>
__global__ __launch_bounds__(256) void gemm_bt(
    const u16* __restrict__ A, int lda, int aoff,
    const u16* __restrict__ BT, const float* __restrict__ bias,
    const float* __restrict__ resid, void* __restrict__ out,
    int M, int N, int K) {
  __shared__ __align__(16) u16 As[64 * SA];
  __shared__ __align__(16) u16 Bs[64 * SA];
  const int tid = threadIdx.x;
  const int wave = tid >> 6, lane = tid & 63;
  const int quad = lane >> 4, l15 = lane & 15;
  const int m0 = blockIdx.x * 64, n0 = blockIdx.y * 64;
  const int srow = tid >> 2, sseg = tid & 3;

  f32x4 acc[4] = {};
  const u16* aptr = A + (size_t)(m0 + srow) * lda + aoff + sseg * 8;
  const u16* bptr = BT + (size_t)((n0 + srow) & (N - 1)) * K + sseg * 8;

  for (int k0 = 0; k0 < K; k0 += 32) {
    uint4 av = *(const uint4*)(aptr + k0);
    uint4 bv = *(const uint4*)(bptr + k0);
    __syncthreads();
    *(uint4*)&As[srow * SA + sseg * 8] = av;
    *(uint4*)&Bs[srow * SA + sseg * 8] = bv;
    __syncthreads();
    bf16x8 a = *(const bf16x8*)&As[(wave * 16 + l15) * SA + quad * 8];
#pragma unroll
    for (int nt = 0; nt < 4; nt++) {
      bf16x8 b = *(const bf16x8*)&Bs[(((nt * 16 + l15) & (N - 1))) * SA + quad * 8];
      acc[nt] = __builtin_amdgcn_mfma_f32_16x16x32_bf16(a, b, acc[nt], 0, 0, 0);
    }
  }
#pragma unroll
  for (int nt = 0; nt < 4; nt++) {
    int gn = n0 + nt * 16 + l15;
    if (gn >= N) continue;
    float bvv = bias[gn];
#pragma unroll
    for (int i = 0; i < 4; i++) {
      int gm = m0 + wave * 16 + quad * 4 + i;
      size_t oidx = (size_t)gm * N + gn;
      float v = acc[nt][i] + bvv;
      if (EPI == 1) ((float*)out)[oidx] = v;
      else ((u16*)out)[oidx] = f2bf(v);
    }
  }
}

// ---------------------------------------------------------------------------
// RoPE + head assembly (unchanged): Qf/Kf [B,NH,T,128] bf16
// ---------------------------------------------------------------------------
__global__ __launch_bounds__(256) void rope_build(
    const u16* __restrict__ qb, const float* __restrict__ qr_pre,
    const u16* __restrict__ kvb, const float* __restrict__ kr_pre,
    u16* __restrict__ Qf, u16* __restrict__ Kf) {
  const int bt = blockIdx.x;
  const int b = bt >> 10, t = bt & 1023;
  const float freq = (float)(t + 1);
  for (int idx = threadIdx.x; idx < 2048; idx += 256) {
    const int h = idx >> 7, d = idx & 127;
    const size_t dst = (((size_t)(b * 16 + h)) * T_ + t) * 128 + d;
    u16 qv, kvv;
    if (d < 64) {
      qv = qb[(size_t)bt * C_ + h * 64 + d];
      kvv = kvb[(size_t)bt * 2048 + h * 64 + d];
    } else {
      const int dd = d - 64;
      {
        const int g = h * 64 + dd;
        const int p = g >> 1;
        const float theta = __expf(-(float)(2 * p) * (9.210340372f / 1024.0f));
        float s, c;
        sincosf(freq * theta, &s, &c);
        const float x0 = qr_pre[(size_t)bt * 1024 + (p << 1)];
        const float x1 = qr_pre[(size_t)bt * 1024 + (p << 1) + 1];
        qv = f2bf((g & 1) ? (x1 * c + x0 * s) : (x0 * c - x1 * s));
      }
      {
        const int p = dd >> 1;
        const float theta = __expf(-(float)(2 * p) * (9.210340372f / 64.0f));
        float s, c;
        sincosf(freq * theta, &s, &c);
        const float x0 = kr_pre[(size_t)bt * 64 + (p << 1)];
        const float x1 = kr_pre[(size_t)bt * 64 + (p << 1) + 1];
        kvv = f2bf((dd & 1) ? (x1 * c + x0 * s) : (x0 * c - x1 * s));
      }
    }
    Qf[dst] = qv;
    Kf[dst] = kvv;
  }
}

// ---------------------------------------------------------------------------
// MFMA flash attention (unchanged from round 3)
// ---------------------------------------------------------------------------
#define QSTR 136
#define VSTR 72

__global__ __launch_bounds__(256) void attn_mfma(
    const u16* __restrict__ Qf, const u16* __restrict__ Kf,
    const u16* __restrict__ kvbuf, u16* __restrict__ attn_o) {
  __shared__ __align__(16) u16 Qs[64 * QSTR];
  __shared__ __align__(16) u16 Ks[64 * QSTR];
  __shared__ __align__(16) u16 Vt[64 * VSTR];
  __shared__ __align__(16) u16 Ps[4][16 * VSTR];

  const int tid = threadIdx.x;
  const int wave = tid >> 6, lane = tid & 63;
  const int quad = lane >> 4, l15 = lane & 15;
  const int qt = blockIdx.x & 15;
  const int h = (blockIdx.x >> 4) & 15;
  const int b = blockIdx.x >> 8;
  const int q0 = qt * 64;
  const size_t bh = (size_t)(b * 16 + h);

  {
    const int r = tid >> 3, cs = (tid & 7) * 16;
    const u16* s0 = &Qf[(bh * T_ + q0 + r) * 128 + cs];
    const u16* s1 = &Qf[(bh * T_ + q0 + r + 32) * 128 + cs];
    *(uint4*)&Qs[r * QSTR + cs] = *(const uint4*)s0;
    *(uint4*)&Qs[r * QSTR + cs + 8] = *(const uint4*)(s0 + 8);
    *(uint4*)&Qs[(r + 32) * QSTR + cs] = *(const uint4*)s1;
    *(uint4*)&Qs[(r + 32) * QSTR + cs + 8] = *(const uint4*)(s1 + 8);
  }

  f32x4 acc_o[4] = {};
  float m_i[4], l_i[4];
#pragma unroll
  for (int i = 0; i < 4; i++) { m_i[i] = -3.0e38f; l_i[i] = 0.0f; }

  for (int kt = 0; kt <= qt; kt++) {
    __syncthreads();
    {
      const int r = tid >> 3, cs = (tid & 7) * 16;
      const u16* s0 = &Kf[(bh * T_ + kt * 64 + r) * 128 + cs];
      const u16* s1 = &Kf[(bh * T_ + kt * 64 + r + 32) * 128 + cs];
      *(uint4*)&Ks[r * QSTR + cs] = *(const uint4*)s0;
      *(uint4*)&Ks[r * QSTR + cs + 8] = *(const uint4*)(s0 + 8);
      *(uint4*)&Ks[(r + 32) * QSTR + cs] = *(const uint4*)s1;
      *(uint4*)&Ks[(r + 32) * QSTR + cs + 8] = *(const uint4*)(s1 + 8);
      const int kpos = tid >> 2, d0 = (tid & 3) * 16;
      const u16* vsrc = &kvbuf[((size_t)(b * T_) + kt * 64 + kpos) * 2048 + 1024 + h * 64 + d0];
      uint4 v0 = *(const uint4*)vsrc;
      uint4 v1 = *(const uint4*)(vsrc + 8);
      u16 tmp[16];
      *(uint4*)tmp = v0;
      *(uint4*)(tmp + 8) = v1;
#pragma unroll
      for (int j = 0; j < 16; j++) Vt[(d0 + j) * VSTR + kpos] = tmp[j];
    }
    __syncthreads();

    f32x4 acc_s[4] = {};
#pragma unroll
    for (int kc = 0; kc < 4; kc++) {
      bf16x8 a = *(const bf16x8*)&Qs[(wave * 16 + l15) * QSTR + kc * 32 + quad * 8];
#pragma unroll
      for (int ng = 0; ng < 4; ng++) {
        bf16x8 bb = *(const bf16x8*)&Ks[(ng * 16 + l15) * QSTR + kc * 32 + quad * 8];
        acc_s[ng] = __builtin_amdgcn_mfma_f32_16x16x32_bf16(a, bb, acc_s[ng], 0, 0, 0);
      }
    }

    float sv[4][4];
#pragma unroll
    for (int ng = 0; ng < 4; ng++)
#pragma unroll
      for (int i = 0; i < 4; i++) {
        float s = acc_s[ng][i] * 0.125f;
        if (kt == qt && (ng * 16 + l15) > (wave * 16 + quad * 4 + i)) s = -3.0e38f;
        sv[ng][i] = s;
      }

    float alpha[4], mx[4];
#pragma unroll
    for (int i = 0; i < 4; i++) {
      float m = fmaxf(fmaxf(sv[0][i], sv[1][i]), fmaxf(sv[2][i], sv[3][i]));
#pragma unroll
      for (int off = 1; off < 16; off <<= 1) m = fmaxf(m, __shfl_xor(m, off, 64));
      float mn = fmaxf(m_i[i], m);
      alpha[i] = __expf(m_i[i] - mn);
      m_i[i] = mn;
      mx[i] = mn;
    }
    float rs[4] = {0.f, 0.f, 0.f, 0.f};
#pragma unroll
    for (int ng = 0; ng < 4; ng++)
#pragma unroll
      for (int i = 0; i < 4; i++) {
        float p = __expf(sv[ng][i] - mx[i]);
        rs[i] += p;
        Ps[wave][(quad * 4 + i) * VSTR + ng * 16 + l15] = f2bf(p);
      }
#pragma unroll
    for (int i = 0; i < 4; i++) {
      float r = rs[i];
#pragma unroll
      for (int off = 1; off < 16; off <<= 1) r += __shfl_xor(r, off, 64);
      l_i[i] = l_i[i] * alpha[i] + r;
    }

#pragma unroll
    for (int ng = 0; ng < 4; ng++)
#pragma unroll
      for (int i = 0; i < 4; i++) acc_o[ng][i] *= alpha[i];
#pragma unroll
    for (int kc = 0; kc < 2; kc++) {
      bf16x8 a = *(const bf16x8*)&Ps[wave][l15 * VSTR + kc * 32 + quad * 8];
#pragma unroll
      for (int ng = 0; ng < 4; ng++) {
        bf16x8 bb = *(const bf16x8*)&Vt[(ng * 16 + l15) * VSTR + kc * 32 + quad * 8];
        acc_o[ng] = __builtin_amdgcn_mfma_f32_16x16x32_bf16(a, bb, acc_o[ng], 0, 0, 0);
      }
    }
  }

  float linv[4];
#pragma unroll
  for (int i = 0; i < 4; i++) linv[i] = 1.0f / l_i[i];
#pragma unroll
  for (int ng = 0; ng < 4; ng++)
#pragma unroll
    for (int i = 0; i < 4; i++) {
      const int qrow = q0 + wave * 16 + quad * 4 + i;
      attn_o[((size_t)(b * T_) + qrow) * C_ + h * 64 + ng * 16 + l15] =
          f2bf(acc_o[ng][i] * linv[i]);
    }
}

// ---------------------------------------------------------------------------
extern "C" void kernel_launch(void* const* d_in, const int* in_sizes, int n_in,
                              void* d_out, int out_size, void* d_ws, size_t ws_size,
                              hipStream_t stream) {
  const float* x = (const float*)d_in[0];
  const float* rms1 = (const float*)d_in[1];
  const float* rms2 = (const float*)d_in[2];
  const float* W_dkv = (const float*)d_in[3];
  const float* b_dkv = (const float*)d_in[4];
  const float* W_kr = (const float*)d_in[5];
  const float* b_kr = (const float*)d_in[6];
  const float* W_qr = (const float*)d_in[7];
  const float* b_qr = (const float*)d_in[8];
  const float* W_kv = (const float*)d_in[9];
  const float* b_kv = (const float*)d_in[10];
  const float* W_q = (const float*)d_in[11];
  const float* b_q = (const float*)d_in[12];
  const float* W_o = (const float*)d_in[13];
  const float* b_o = (const float*)d_in[14];
  const float* W_f1 = (const float*)d_in[15];
  const float* b_f1 = (const float*)d_in[16];
  const float* W_f2 = (const float*)d_in[17];
  const float* b_f2 = (const float*)d_in[18];
  float* out = (float*)d_out;

  char* ws = (char*)d_ws;
  size_t off = 0;
  auto alloc = [&](size_t bytes) -> void* {
    void* p = ws + off;
    off += (bytes + 255) & ~(size_t)255;
    return p;
  };
  u16* WT_dkv = (u16*)alloc((size_t)1024 * 1024 * 2);
  u16* WT_kr  = (u16*)alloc((size_t)64 * 1024 * 2);
  u16* WT_qr  = (u16*)alloc((size_t)1024 * 1024 * 2);
  u16* WT_kv  = (u16*)alloc((size_t)2048 * 512 * 2);
  u16* WT_q   = (u16*)alloc((size_t)1024 * 512 * 2);
  u16* WT_o   = (u16*)alloc((size_t)1024 * 1024 * 2);
  u16* WT_f1  = (u16*)alloc((size_t)4096 * 1024 * 2);
  u16* WT_f2  = (u16*)alloc((size_t)1024 * 4096 * 2);
  u16* xn1    = (u16*)alloc((size_t)4096 * 1024 * 2);
  u16* comp   = (u16*)alloc((size_t)4096 * 1024 * 2);
  float* kr_pre = (float*)alloc((size_t)4096 * 64 * 4);
  float* qr_pre = (float*)alloc((size_t)4096 * 1024 * 4);
  u16* kvbuf  = (u16*)alloc((size_t)4096 * 2048 * 2);
  u16* qbuf   = (u16*)alloc((size_t)4096 * 1024 * 2);
  u16* Qf     = (u16*)alloc((size_t)64 * 1024 * 128 * 2);
  u16* Kf     = (u16*)alloc((size_t)64 * 1024 * 128 * 2);
  u16* attn_o = (u16*)alloc((size_t)4096 * 1024 * 2);
  float* hbuf = (float*)alloc((size_t)4096 * 1024 * 4);
  u16* hn     = (u16*)alloc((size_t)4096 * 1024 * 2);
  u16* hid    = (u16*)alloc((size_t)4096 * 4096 * 2);

  dim3 tb(32, 8);
  transpose_kernel<<<dim3(32, 32), tb, 0, stream>>>(W_dkv, WT_dkv, 1024, 1024);
  transpose_kernel<<<dim3(2, 32), tb, 0, stream>>>(W_kr, WT_kr, 1024, 64);
  transpose_kernel<<<dim3(32, 32), tb, 0, stream>>>(W_qr, WT_qr, 1024, 1024);
  transpose_kernel<<<dim3(64, 16), tb, 0, stream>>>(W_kv, WT_kv, 512, 2048);
  transpose_kernel<<<dim3(32, 16), tb, 0, stream>>>(W_q, WT_q, 512, 1024);
  transpose_kernel<<<dim3(32, 32), tb, 0, stream>>>(W_o, WT_o, 1024, 1024);
  transpose_kernel<<<dim3(128, 32), tb, 0, stream>>>(W_f1, WT_f1, 1024, 4096);
  transpose_kernel<<<dim3(32, 128), tb, 0, stream>>>(W_f2, WT_f2, 4096, 1024);

  rmsnorm_kernel<<<4096, 256, 0, stream>>>(x, rms1, xn1);

  gemm128<0><<<dim3(32, 8), 256, 0, stream>>>(xn1, 1024, 0, WT_dkv, b_dkv, nullptr, comp, 4096, 1024, 1024);
  gemm_bt<1><<<dim3(64, 1), 256, 0, stream>>>(comp, 1024, 0, WT_kr, b_kr, nullptr, kr_pre, 4096, 64, 1024);
  gemm128<1><<<dim3(32, 8), 256, 0, stream>>>(comp, 1024, 0, WT_qr, b_qr, nullptr, qr_pre, 4096, 1024, 1024);
  gemm128<0><<<dim3(32, 16), 256, 0, stream>>>(comp, 1024, 0, WT_kv, b_kv, nullptr, kvbuf, 4096, 2048, 512);
  gemm128<0><<<dim3(32, 8), 256, 0, stream>>>(comp, 1024, 512, WT_q, b_q, nullptr, qbuf, 4096, 1024, 512);

  rope_build<<<4096, 256, 0, stream>>>(qbuf, qr_pre, kvbuf, kr_pre, Qf, Kf);

  attn_mfma<<<B_ * NH_ * (T_ / 64), 256, 0, stream>>>(Qf, Kf, kvbuf, attn_o);

  gemm128<3><<<dim3(32, 8), 256, 0, stream>>>(attn_o, 1024, 0, WT_o, b_o, x, hbuf, 4096, 1024, 1024);

  rmsnorm_kernel<<<4096, 256, 0, stream>>>(hbuf, rms2, hn);

  gemm128<2><<<dim3(32, 32), 256, 0, stream>>>(hn, 1024, 0, WT_f1, b_f1, nullptr, hid, 4096, 4096, 1024);
  gemm128<3><<<dim3(32, 8), 256, 0, stream>>>(hid, 4096, 0, WT_f2, b_f2, hbuf, out, 4096, 1024, 4096);
}

// Round 5
// 500.424 us; speedup vs baseline: 1.1668x; 1.1668x over previous
//
#include <hip/hip_runtime.h>

typedef unsigned int u32;
typedef unsigned short u16;
typedef __bf16 bf16x8 __attribute__((ext_vector_type(8)));
typedef float f32x4 __attribute__((ext_vector_type(4)));

#define B_ 4
#define T_ 1024
#define C_ 1024
#define NH_ 16
#define L_ 512
#define DHR_ 64
#define FF_ 4096

typedef __attribute__((address_space(3))) u32 as3_u32;
typedef __attribute__((address_space(1))) u32 as1_u32;

__device__ __forceinline__ void gld16(const u16* g, u16* l) {
  __builtin_amdgcn_global_load_lds((const as1_u32*)g, (as3_u32*)l, 16, 0, 0);
}

__device__ __forceinline__ float bf2f(u16 u) {
  union { u32 i; float f; } v; v.i = ((u32)u) << 16; return v.f;
}
__device__ __forceinline__ u16 f2bf(float f) {
  union { float f; u32 i; } v; v.f = f;
  u32 r = (v.i + 0x7FFFu + ((v.i >> 16) & 1u)) >> 16;
  return (u16)r;
}

// ---------------------------------------------------------------------------
// Weight transpose + f32->bf16 convert: in f32 [R,C] -> out bf16 [C,R]
// ---------------------------------------------------------------------------
__global__ void transpose_kernel(const float* __restrict__ in, u16* __restrict__ outp,
                                 int R, int C) {
  __shared__ float tile[32][33];
  int bx = blockIdx.x * 32;
  int by = blockIdx.y * 32;
  int tx = threadIdx.x, ty = threadIdx.y;
  for (int i = ty; i < 32; i += 8)
    tile[i][tx] = in[(size_t)(by + i) * C + bx + tx];
  __syncthreads();
  for (int i = ty; i < 32; i += 8)
    outp[(size_t)(bx + i) * R + by + tx] = f2bf(tile[tx][i]);
}

// ---------------------------------------------------------------------------
// RMSNorm: row-per-block, C=1024, f32 in, f32 weight, bf16 out
// ---------------------------------------------------------------------------
__global__ __launch_bounds__(256) void rmsnorm_kernel(const float* __restrict__ xin,
                                                      const float* __restrict__ w,
                                                      u16* __restrict__ outp) {
  const int row = blockIdx.x;
  const int tid = threadIdx.x;
  const float* xp = xin + (size_t)row * C_;
  float v[4];
#pragma unroll
  for (int i = 0; i < 4; i++) v[i] = xp[tid + 256 * i];
  float ss = v[0] * v[0] + v[1] * v[1] + v[2] * v[2] + v[3] * v[3];
#pragma unroll
  for (int o = 32; o > 0; o >>= 1) ss += __shfl_down(ss, o, 64);
  __shared__ float red[4];
  if ((tid & 63) == 0) red[tid >> 6] = ss;
  __syncthreads();
  ss = red[0] + red[1] + red[2] + red[3];
  float scale = rsqrtf(ss * (1.0f / 1024.0f) + 1e-6f);
  u16* op = outp + (size_t)row * C_;
#pragma unroll
  for (int i = 0; i < 4; i++)
    op[tid + 256 * i] = f2bf(v[i] * scale * w[tid + 256 * i]);
}

// ---------------------------------------------------------------------------
// Shared 128x128 GEMM body (m97 structure). BT is [N,K]-shaped (Kfull = row
// stride); loop covers Klen starting at koff. EPI: 0 bf16 | 1 f32 |
// 2 bf16+gelu | 3 f32+f32 resid | 4 f32 partial (no bias).
// NCLIP: skip output columns >= N (for the N=64 kr projection).
// ---------------------------------------------------------------------------
template<int EPI, bool NCLIP>
__device__ __forceinline__ void g128_body(
    u16* As, u16* Bs,
    const u16* __restrict__ A, int lda, int aoff,
    const u16* __restrict__ BT, const float* __restrict__ bias,
    const float* __restrict__ resid, void* __restrict__ out,
    int N, int Kfull, int Klen, int m0, int n0, int koff) {
  const int tid = threadIdx.x;
  const int wave = tid >> 6, lane = tid & 63;
  const int wm = wave >> 1, wn = wave & 1;
  const int quad = lane >> 4, l15 = lane & 15;
  const int row = tid >> 2, seg = tid & 3;

  const u16* aP = A + (size_t)(m0 + row) * lda + aoff + koff + seg * 8;
  const u16* bP = BT + (size_t)(n0 + row) * Kfull + koff + seg * 8;
  u16* aL = As + row * 32 + seg * 8;
  u16* bL = Bs + row * 32 + seg * 8;
  const size_t aStep = (size_t)64 * lda;
  const size_t bStep = (size_t)64 * Kfull;

  f32x4 acc[4][4] = {};

  for (int k0 = 0; k0 < Klen; k0 += 32) {
    gld16(aP + k0, aL);
    gld16(aP + k0 + aStep, aL + 64 * 32);
    gld16(bP + k0, bL);
    gld16(bP + k0 + bStep, bL + 64 * 32);
    __syncthreads();
    bf16x8 af[4], bf[4];
#pragma unroll
    for (int mt = 0; mt < 4; mt++)
      af[mt] = *(const bf16x8*)&As[(wm * 64 + mt * 16 + l15) * 32 + quad * 8];
#pragma unroll
    for (int nt = 0; nt < 4; nt++)
      bf[nt] = *(const bf16x8*)&Bs[(wn * 64 + nt * 16 + l15) * 32 + quad * 8];
#pragma unroll
    for (int mt = 0; mt < 4; mt++)
#pragma unroll
      for (int nt = 0; nt < 4; nt++)
        acc[mt][nt] = __builtin_amdgcn_mfma_f32_16x16x32_bf16(af[mt], bf[nt], acc[mt][nt], 0, 0, 0);
    __syncthreads();
  }

#pragma unroll
  for (int nt = 0; nt < 4; nt++) {
    const int gn = n0 + wn * 64 + nt * 16 + l15;
    if (NCLIP && gn >= N) continue;
    const float bvv = (EPI == 4) ? 0.0f : bias[gn];
#pragma unroll
    for (int mt = 0; mt < 4; mt++) {
#pragma unroll
      for (int i = 0; i < 4; i++) {
        const int gm = m0 + wm * 64 + mt * 16 + quad * 4 + i;
        const size_t oidx = (size_t)gm * N + gn;
        float v = acc[mt][nt][i] + bvv;
        if (EPI == 2) {
          float xg = v;
          v = 0.5f * xg * (1.0f + tanhf(0.7978845608028654f * (xg + 0.044715f * xg * xg * xg)));
        }
        if (EPI == 3) v += resid[oidx];
        if (EPI == 1 || EPI == 3 || EPI == 4) ((float*)out)[oidx] = v;
        else ((u16*)out)[oidx] = f2bf(v);
      }
    }
  }
}

template<int EPI>
__global__ __launch_bounds__(256) void gemm128(
    const u16* __restrict__ A, int lda, int aoff,
    const u16* __restrict__ BT, const float* __restrict__ bias,
    const float* __restrict__ resid, void* __restrict__ out,
    int M, int N, int K) {
  __shared__ __align__(16) u16 As[128 * 32];
  __shared__ __align__(16) u16 Bs[128 * 32];
  g128_body<EPI, false>(As, Bs, A, lda, aoff, BT, bias, resid, out,
                        N, K, K, blockIdx.x * 128, blockIdx.y * 128, 0);
}

// split-K (blockIdx.z = K chunk) -> f32 partials, no bias
__global__ __launch_bounds__(256) void gemm128_splitk(
    const u16* __restrict__ A, int lda, const u16* __restrict__ BT,
    float* __restrict__ part, int N, int Kfull, int Klen) {
  __shared__ __align__(16) u16 As[128 * 32];
  __shared__ __align__(16) u16 Bs[128 * 32];
  const int z = blockIdx.z;
  g128_body<4, false>(As, Bs, A, lda, 0, BT, nullptr, nullptr,
                      part + (size_t)z * 4096 * N,
                      N, Kfull, Klen, blockIdx.x * 128, blockIdx.y * 128, z * Klen);
}

// out = h + bias + part[0] + part[1]   (f2 epilogue)
__global__ __launch_bounds__(256) void f2_reduce(
    const float* __restrict__ part, const float* __restrict__ h,
    const float* __restrict__ bias, float* __restrict__ out) {
  const size_t base = (size_t)blockIdx.x * 1024;
#pragma unroll
  for (int i = 0; i < 4; i++) {
    const int col = threadIdx.x + 256 * i;
    out[base + col] = h[base + col] + bias[col] + part[base + col] +
                      part[(size_t)4096 * 1024 + base + col];
  }
}

// ---------------------------------------------------------------------------
// Fused qr/kr/kv/q projections, all reading comp. grid (32, 33).
// ny<8: qr(f32,N=1024,K=1024) | ny==8: kr(f32,N=64,K=1024,NCLIP)
// ny in 9..24: kv(bf16,N=2048,K=512) | ny in 25..32: q(bf16,N=1024,K=512,aoff=512)
// ---------------------------------------------------------------------------
__global__ __launch_bounds__(256) void proj_fused(
    const u16* __restrict__ comp,
    const u16* __restrict__ WT_qr, const float* __restrict__ b_qr, float* __restrict__ qr_pre,
    const u16* __restrict__ WT_kr, const float* __restrict__ b_kr, float* __restrict__ kr_pre,
    const u16* __restrict__ WT_kv, const float* __restrict__ b_kv, u16* __restrict__ kvbuf,
    const u16* __restrict__ WT_q, const float* __restrict__ b_q, u16* __restrict__ qbuf) {
  __shared__ __align__(16) u16 As[128 * 32];
  __shared__ __align__(16) u16 Bs[128 * 32];
  const int m0 = blockIdx.x * 128;
  const int ny = blockIdx.y;
  if (ny < 8)
    g128_body<1, false>(As, Bs, comp, 1024, 0, WT_qr, b_qr, nullptr, qr_pre, 1024, 1024, 1024, m0, ny * 128, 0);
  else if (ny == 8)
    g128_body<1, true>(As, Bs, comp, 1024, 0, WT_kr, b_kr, nullptr, kr_pre, 64, 1024, 1024, m0, 0, 0);
  else if (ny < 25)
    g128_body<0, false>(As, Bs, comp, 1024, 0, WT_kv, b_kv, nullptr, kvbuf, 2048, 512, 512, m0, (ny - 9) * 128, 0);
  else
    g128_body<0, false>(As, Bs, comp, 1024, 512, WT_q, b_q, nullptr, qbuf, 1024, 512, 512, m0, (ny - 25) * 128, 0);
}

// ---------------------------------------------------------------------------
// RoPE + head assembly (unchanged): Qf/Kf [B,NH,T,128] bf16
// ---------------------------------------------------------------------------
__global__ __launch_bounds__(256) void rope_build(
    const u16* __restrict__ qb, const float* __restrict__ qr_pre,
    const u16* __restrict__ kvb, const float* __restrict__ kr_pre,
    u16* __restrict__ Qf, u16* __restrict__ Kf) {
  const int bt = blockIdx.x;
  const int b = bt >> 10, t = bt & 1023;
  const float freq = (float)(t + 1);
  for (int idx = threadIdx.x; idx < 2048; idx += 256) {
    const int h = idx >> 7, d = idx & 127;
    const size_t dst = (((size_t)(b * 16 + h)) * T_ + t) * 128 + d;
    u16 qv, kvv;
    if (d < 64) {
      qv = qb[(size_t)bt * C_ + h * 64 + d];
      kvv = kvb[(size_t)bt * 2048 + h * 64 + d];
    } else {
      const int dd = d - 64;
      {
        const int g = h * 64 + dd;
        const int p = g >> 1;
        const float theta = __expf(-(float)(2 * p) * (9.210340372f / 1024.0f));
        float s, c;
        sincosf(freq * theta, &s, &c);
        const float x0 = qr_pre[(size_t)bt * 1024 + (p << 1)];
        const float x1 = qr_pre[(size_t)bt * 1024 + (p << 1) + 1];
        qv = f2bf((g & 1) ? (x1 * c + x0 * s) : (x0 * c - x1 * s));
      }
      {
        const int p = dd >> 1;
        const float theta = __expf(-(float)(2 * p) * (9.210340372f / 64.0f));
        float s, c;
        sincosf(freq * theta, &s, &c);
        const float x0 = kr_pre[(size_t)bt * 64 + (p << 1)];
        const float x1 = kr_pre[(size_t)bt * 64 + (p << 1) + 1];
        kvv = f2bf((dd & 1) ? (x1 * c + x0 * s) : (x0 * c - x1 * s));
      }
    }
    Qf[dst] = qv;
    Kf[dst] = kvv;
  }
}

// ---------------------------------------------------------------------------
// V transpose: kvbuf V-half [B,T,NH,64] -> Vf [B,NH,64,T]
// ---------------------------------------------------------------------------
__global__ __launch_bounds__(256) void vtrans_kernel(
    const u16* __restrict__ kvb, u16* __restrict__ Vf) {
  __shared__ u16 tile[64][72];
  const int bh = blockIdx.x, t0 = blockIdx.y * 64;
  const int b = bh >> 4, h = bh & 15;
  const int r = threadIdx.x >> 2, seg = (threadIdx.x & 3) * 16;
  const u16* src = &kvb[((size_t)(b * 1024) + t0 + r) * 2048 + 1024 + h * 64 + seg];
  *(uint4*)&tile[r][seg] = *(const uint4*)src;
  *(uint4*)&tile[r][seg + 8] = *(const uint4*)(src + 8);
  __syncthreads();
  const int d = threadIdx.x >> 2, ts = (threadIdx.x & 3) * 16;
  u16 tmp[16];
#pragma unroll
  for (int j = 0; j < 16; j++) tmp[j] = tile[ts + j][d];
  u16* dst = &Vf[((size_t)bh * 64 + d) * 1024 + t0 + ts];
  *(uint4*)dst = *(uint4*)tmp;
  *(uint4*)(dst + 8) = *(uint4*)(tmp + 8);
}

// ---------------------------------------------------------------------------
// MFMA flash attention v2: Q frags in registers, V pre-transposed (Vf).
// Block = (b, h, 64-row q-tile), 256 thr = 4 waves; K-tiles of 64.
// ---------------------------------------------------------------------------
#define KSTR 136
#define VSTR 72

__global__ __launch_bounds__(256) void attn_mfma(
    const u16* __restrict__ Qf, const u16* __restrict__ Kf,
    const u16* __restrict__ Vf, u16* __restrict__ attn_o) {
  __shared__ __align__(16) u16 Ks[64 * KSTR];
  __shared__ __align__(16) u16 Vt[64 * VSTR];
  __shared__ __align__(16) u16 Ps[4][16 * VSTR];

  const int tid = threadIdx.x;
  const int wave = tid >> 6, lane = tid & 63;
  const int quad = lane >> 4, l15 = lane & 15;
  const int qt = blockIdx.x & 15;
  const int h = (blockIdx.x >> 4) & 15;
  const int b = blockIdx.x >> 8;
  const int q0 = qt * 64;
  const size_t bh = (size_t)(b * 16 + h);

  // Q A-fragments straight from global into registers (16B contiguous each)
  bf16x8 qfrag[4];
  {
    const u16* qb = &Qf[(bh * T_ + q0 + wave * 16 + l15) * 128 + quad * 8];
#pragma unroll
    for (int kc = 0; kc < 4; kc++) qfrag[kc] = *(const bf16x8*)(qb + kc * 32);
  }

  f32x4 acc_o[4] = {};
  float m_i[4], l_i[4];
#pragma unroll
  for (int i = 0; i < 4; i++) { m_i[i] = -3.0e38f; l_i[i] = 0.0f; }

  const int kr_ = tid >> 3, kcs = (tid & 7) * 16;  // K staging coords
  const int vd = tid >> 2, vts = (tid & 3) * 16;   // V staging coords

  for (int kt = 0; kt <= qt; kt++) {
    __syncthreads();
    {  // stage K (vectorized, padded) + V (already transposed in Vf)
      const u16* s0 = &Kf[(bh * T_ + kt * 64 + kr_) * 128 + kcs];
      const u16* s1 = s0 + 32 * 128;
      *(uint4*)&Ks[kr_ * KSTR + kcs] = *(const uint4*)s0;
      *(uint4*)&Ks[kr_ * KSTR + kcs + 8] = *(const uint4*)(s0 + 8);
      *(uint4*)&Ks[(kr_ + 32) * KSTR + kcs] = *(const uint4*)s1;
      *(uint4*)&Ks[(kr_ + 32) * KSTR + kcs + 8] = *(const uint4*)(s1 + 8);
      const u16* vs = &Vf[(bh * 64 + vd) * 1024 + kt * 64 + vts];
      *(uint4*)&Vt[vd * VSTR + vts] = *(const uint4*)vs;
      *(uint4*)&Vt[vd * VSTR + vts + 8] = *(const uint4*)(vs + 8);
    }
    __syncthreads();

    // S = Q K^T
    f32x4 acc_s[4] = {};
#pragma unroll
    for (int kc = 0; kc < 4; kc++) {
#pragma unroll
      for (int ng = 0; ng < 4; ng++) {
        bf16x8 bb = *(const bf16x8*)&Ks[(ng * 16 + l15) * KSTR + kc * 32 + quad * 8];
        acc_s[ng] = __builtin_amdgcn_mfma_f32_16x16x32_bf16(qfrag[kc], bb, acc_s[ng], 0, 0, 0);
      }
    }

    float sv[4][4];
#pragma unroll
    for (int ng = 0; ng < 4; ng++)
#pragma unroll
      for (int i = 0; i < 4; i++) {
        float s = acc_s[ng][i] * 0.125f;
        if (kt == qt && (ng * 16 + l15) > (wave * 16 + quad * 4 + i)) s = -3.0e38f;
        sv[ng][i] = s;
      }

    float alpha[4], mx[4];
#pragma unroll
    for (int i = 0; i < 4; i++) {
      float m = fmaxf(fmaxf(sv[0][i], sv[1][i]), fmaxf(sv[2][i], sv[3][i]));
#pragma unroll
      for (int off = 1; off < 16; off <<= 1) m = fmaxf(m, __shfl_xor(m, off, 64));
      float mn = fmaxf(m_i[i], m);
      alpha[i] = __expf(m_i[i] - mn);
      m_i[i] = mn;
      mx[i] = mn;
    }
    float rs[4] = {0.f, 0.f, 0.f, 0.f};
#pragma unroll
    for (int ng = 0; ng < 4; ng++)
#pragma unroll
      for (int i = 0; i < 4; i++) {
        float p = __expf(sv[ng][i] - mx[i]);
        rs[i] += p;
        Ps[wave][(quad * 4 + i) * VSTR + ng * 16 + l15] = f2bf(p);
      }
#pragma unroll
    for (int i = 0; i < 4; i++) {
      float r = rs[i];
#pragma unroll
      for (int off = 1; off < 16; off <<= 1) r += __shfl_xor(r, off, 64);
      l_i[i] = l_i[i] * alpha[i] + r;
    }

    // O = O*alpha + P @ V  (Ps wave-private: lgkmcnt ordering suffices)
#pragma unroll
    for (int ng = 0; ng < 4; ng++)
#pragma unroll
      for (int i = 0; i < 4; i++) acc_o[ng][i] *= alpha[i];
#pragma unroll
    for (int kc = 0; kc < 2; kc++) {
      bf16x8 a = *(const bf16x8*)&Ps[wave][l15 * VSTR + kc * 32 + quad * 8];
#pragma unroll
      for (int ng = 0; ng < 4; ng++) {
        bf16x8 bb = *(const bf16x8*)&Vt[(ng * 16 + l15) * VSTR + kc * 32 + quad * 8];
        acc_o[ng] = __builtin_amdgcn_mfma_f32_16x16x32_bf16(a, bb, acc_o[ng], 0, 0, 0);
      }
    }
  }

  float linv[4];
#pragma unroll
  for (int i = 0; i < 4; i++) linv[i] = 1.0f / l_i[i];
#pragma unroll
  for (int ng = 0; ng < 4; ng++)
#pragma unroll
    for (int i = 0; i < 4; i++) {
      const int qrow = q0 + wave * 16 + quad * 4 + i;
      attn_o[((size_t)(b * T_) + qrow) * C_ + h * 64 + ng * 16 + l15] =
          f2bf(acc_o[ng][i] * linv[i]);
    }
}

// ---------------------------------------------------------------------------
extern "C" void kernel_launch(void* const* d_in, const int* in_sizes, int n_in,
                              void* d_out, int out_size, void* d_ws, size_t ws_size,
                              hipStream_t stream) {
  const float* x = (const float*)d_in[0];
  const float* rms1 = (const float*)d_in[1];
  const float* rms2 = (const float*)d_in[2];
  const float* W_dkv = (const float*)d_in[3];
  const float* b_dkv = (const float*)d_in[4];
  const float* W_kr = (const float*)d_in[5];
  const float* b_kr = (const float*)d_in[6];
  const float* W_qr = (const float*)d_in[7];
  const float* b_qr = (const float*)d_in[8];
  const float* W_kv = (const float*)d_in[9];
  const float* b_kv = (const float*)d_in[10];
  const float* W_q = (const float*)d_in[11];
  const float* b_q = (const float*)d_in[12];
  const float* W_o = (const float*)d_in[13];
  const float* b_o = (const float*)d_in[14];
  const float* W_f1 = (const float*)d_in[15];
  const float* b_f1 = (const float*)d_in[16];
  const float* W_f2 = (const float*)d_in[17];
  const float* b_f2 = (const float*)d_in[18];
  float* out = (float*)d_out;

  char* ws = (char*)d_ws;
  size_t off = 0;
  auto alloc = [&](size_t bytes) -> void* {
    void* p = ws + off;
    off += (bytes + 255) & ~(size_t)255;
    return p;
  };
  u16* WT_dkv = (u16*)alloc((size_t)1024 * 1024 * 2);
  u16* WT_kr  = (u16*)alloc((size_t)128 * 1024 * 2);  // 64 real rows + 64 pad
  u16* WT_qr  = (u16*)alloc((size_t)1024 * 1024 * 2);
  u16* WT_kv  = (u16*)alloc((size_t)2048 * 512 * 2);
  u16* WT_q   = (u16*)alloc((size_t)1024 * 512 * 2);
  u16* WT_o   = (u16*)alloc((size_t)1024 * 1024 * 2);
  u16* WT_f1  = (u16*)alloc((size_t)4096 * 1024 * 2);
  u16* WT_f2  = (u16*)alloc((size_t)1024 * 4096 * 2);
  u16* xn1    = (u16*)alloc((size_t)4096 * 1024 * 2);
  u16* comp   = (u16*)alloc((size_t)4096 * 1024 * 2);
  float* kr_pre = (float*)alloc((size_t)4096 * 64 * 4);
  float* qr_pre = (float*)alloc((size_t)4096 * 1024 * 4);
  u16* kvbuf  = (u16*)alloc((size_t)4096 * 2048 * 2);
  u16* qbuf   = (u16*)alloc((size_t)4096 * 1024 * 2);
  u16* Qf     = (u16*)alloc((size_t)64 * 1024 * 128 * 2);  // 16 MB
  u16* Kf     = (u16*)alloc((size_t)64 * 1024 * 128 * 2);  // 16 MB (contig after Qf)
  u16* Vf     = (u16*)alloc((size_t)64 * 64 * 1024 * 2);   // 8 MB
  u16* attn_o = (u16*)alloc((size_t)4096 * 1024 * 2);
  float* hbuf = (float*)alloc((size_t)4096 * 1024 * 4);
  u16* hn     = (u16*)alloc((size_t)4096 * 1024 * 2);
  u16* hid    = (u16*)alloc((size_t)4096 * 4096 * 2);
  // f2 split-K partials (2 x 16 MB f32) alias Qf+Kf (dead by f2 time)
  float* partial = (float*)Qf;

  dim3 tb(32, 8);
  transpose_kernel<<<dim3(32, 32), tb, 0, stream>>>(W_dkv, WT_dkv, 1024, 1024);
  transpose_kernel<<<dim3(2, 32), tb, 0, stream>>>(W_kr, WT_kr, 1024, 64);
  transpose_kernel<<<dim3(32, 32), tb, 0, stream>>>(W_qr, WT_qr, 1024, 1024);
  transpose_kernel<<<dim3(64, 16), tb, 0, stream>>>(W_kv, WT_kv, 512, 2048);
  transpose_kernel<<<dim3(32, 16), tb, 0, stream>>>(W_q, WT_q, 512, 1024);
  transpose_kernel<<<dim3(32, 32), tb, 0, stream>>>(W_o, WT_o, 1024, 1024);
  transpose_kernel<<<dim3(128, 32), tb, 0, stream>>>(W_f1, WT_f1, 1024, 4096);
  transpose_kernel<<<dim3(32, 128), tb, 0, stream>>>(W_f2, WT_f2, 4096, 1024);

  rmsnorm_kernel<<<4096, 256, 0, stream>>>(x, rms1, xn1);

  gemm128<0><<<dim3(32, 8), 256, 0, stream>>>(xn1, 1024, 0, WT_dkv, b_dkv, nullptr, comp, 4096, 1024, 1024);

  proj_fused<<<dim3(32, 33), 256, 0, stream>>>(comp,
      WT_qr, b_qr, qr_pre, WT_kr, b_kr, kr_pre,
      WT_kv, b_kv, kvbuf, WT_q, b_q, qbuf);

  rope_build<<<4096, 256, 0, stream>>>(qbuf, qr_pre, kvbuf, kr_pre, Qf, Kf);
  vtrans_kernel<<<dim3(64, 16), 256, 0, stream>>>(kvbuf, Vf);

  attn_mfma<<<B_ * NH_ * (T_ / 64), 256, 0, stream>>>(Qf, Kf, Vf, attn_o);

  gemm128<3><<<dim3(32, 8), 256, 0, stream>>>(attn_o, 1024, 0, WT_o, b_o, x, hbuf, 4096, 1024, 1024);

  rmsnorm_kernel<<<4096, 256, 0, stream>>>(hbuf, rms2, hn);

  gemm128<2><<<dim3(32, 32), 256, 0, stream>>>(hn, 1024, 0, WT_f1, b_f1, nullptr, hid, 4096, 4096, 1024);

  gemm128_splitk<<<dim3(32, 8, 2), 256, 0, stream>>>(hid, 4096, WT_f2, partial, 1024, 4096, 2048);
  f2_reduce<<<4096, 256, 0, stream>>>(partial, hbuf, b_f2, out);
}

// Round 6
// 471.509 us; speedup vs baseline: 1.2383x; 1.0613x over previous
//
#include <hip/hip_runtime.h>

typedef unsigned int u32;
typedef unsigned short u16;
typedef __bf16 bf16x8 __attribute__((ext_vector_type(8)));
typedef float f32x4 __attribute__((ext_vector_type(4)));

#define B_ 4
#define T_ 1024
#define C_ 1024
#define NH_ 16
#define L_ 512
#define DHR_ 64
#define FF_ 4096

typedef __attribute__((address_space(3))) u32 as3_u32;
typedef __attribute__((address_space(1))) u32 as1_u32;

__device__ __forceinline__ void gld16(const u16* g, u16* l) {
  __builtin_amdgcn_global_load_lds((const as1_u32*)g, (as3_u32*)l, 16, 0, 0);
}

__device__ __forceinline__ float bf2f(u16 u) {
  union { u32 i; float f; } v; v.i = ((u32)u) << 16; return v.f;
}
__device__ __forceinline__ u16 f2bf(float f) {
  union { float f; u32 i; } v; v.f = f;
  u32 r = (v.i + 0x7FFFu + ((v.i >> 16) & 1u)) >> 16;
  return (u16)r;
}

// ---------------------------------------------------------------------------
// Fused weight transpose: all 8 weights in ONE dispatch.
// f32 [R,C] -> bf16 [C,R], 32x32 tiles, block (32,8).
// ---------------------------------------------------------------------------
struct TransArgs {
  const float* src[8];
  u16* dst[8];
  int R[8], C[8];
  int base[9];  // cumulative tile offsets
};

__global__ void transpose_all(TransArgs ta) {
  __shared__ float tile[32][33];
  const int bid = blockIdx.x;
  int w = 0;
#pragma unroll
  for (int i = 1; i < 8; i++) w += (bid >= ta.base[i]);
  const int local = bid - ta.base[w];
  const int R = ta.R[w], C = ta.C[w];
  const int ctiles = C >> 5;
  const int bx = (local % ctiles) * 32;
  const int by = (local / ctiles) * 32;
  const float* in = ta.src[w];
  u16* outp = ta.dst[w];
  const int tx = threadIdx.x, ty = threadIdx.y;
  for (int i = ty; i < 32; i += 8)
    tile[i][tx] = in[(size_t)(by + i) * C + bx + tx];
  __syncthreads();
  for (int i = ty; i < 32; i += 8)
    outp[(size_t)(bx + i) * R + by + tx] = f2bf(tile[tx][i]);
}

// ---------------------------------------------------------------------------
// RMSNorm: row-per-block, C=1024, f32 in, f32 weight, bf16 out
// ---------------------------------------------------------------------------
__global__ __launch_bounds__(256) void rmsnorm_kernel(const float* __restrict__ xin,
                                                      const float* __restrict__ w,
                                                      u16* __restrict__ outp) {
  const int row = blockIdx.x;
  const int tid = threadIdx.x;
  const float* xp = xin + (size_t)row * C_;
  float v[4];
#pragma unroll
  for (int i = 0; i < 4; i++) v[i] = xp[tid + 256 * i];
  float ss = v[0] * v[0] + v[1] * v[1] + v[2] * v[2] + v[3] * v[3];
#pragma unroll
  for (int o = 32; o > 0; o >>= 1) ss += __shfl_down(ss, o, 64);
  __shared__ float red[4];
  if ((tid & 63) == 0) red[tid >> 6] = ss;
  __syncthreads();
  ss = red[0] + red[1] + red[2] + red[3];
  float scale = rsqrtf(ss * (1.0f / 1024.0f) + 1e-6f);
  u16* op = outp + (size_t)row * C_;
#pragma unroll
  for (int i = 0; i < 4; i++)
    op[tid + 256 * i] = f2bf(v[i] * scale * w[tid + 256 * i]);
}

// ---------------------------------------------------------------------------
// Shared 128x128 GEMM body (m97 structure). EPI: 0 bf16 | 1 f32 |
// 2 bf16+gelu | 3 f32+f32 resid | 4 f32 partial (no bias).
// ---------------------------------------------------------------------------
template<int EPI, bool NCLIP>
__device__ __forceinline__ void g128_body(
    u16* As, u16* Bs,
    const u16* __restrict__ A, int lda, int aoff,
    const u16* __restrict__ BT, const float* __restrict__ bias,
    const float* __restrict__ resid, void* __restrict__ out,
    int N, int Kfull, int Klen, int m0, int n0, int koff) {
  const int tid = threadIdx.x;
  const int wave = tid >> 6, lane = tid & 63;
  const int wm = wave >> 1, wn = wave & 1;
  const int quad = lane >> 4, l15 = lane & 15;
  const int row = tid >> 2, seg = tid & 3;

  const u16* aP = A + (size_t)(m0 + row) * lda + aoff + koff + seg * 8;
  const u16* bP = BT + (size_t)(n0 + row) * Kfull + koff + seg * 8;
  u16* aL = As + row * 32 + seg * 8;
  u16* bL = Bs + row * 32 + seg * 8;
  const size_t aStep = (size_t)64 * lda;
  const size_t bStep = (size_t)64 * Kfull;

  f32x4 acc[4][4] = {};

  for (int k0 = 0; k0 < Klen; k0 += 32) {
    gld16(aP + k0, aL);
    gld16(aP + k0 + aStep, aL + 64 * 32);
    gld16(bP + k0, bL);
    gld16(bP + k0 + bStep, bL + 64 * 32);
    __syncthreads();
    bf16x8 af[4], bf[4];
#pragma unroll
    for (int mt = 0; mt < 4; mt++)
      af[mt] = *(const bf16x8*)&As[(wm * 64 + mt * 16 + l15) * 32 + quad * 8];
#pragma unroll
    for (int nt = 0; nt < 4; nt++)
      bf[nt] = *(const bf16x8*)&Bs[(wn * 64 + nt * 16 + l15) * 32 + quad * 8];
#pragma unroll
    for (int mt = 0; mt < 4; mt++)
#pragma unroll
      for (int nt = 0; nt < 4; nt++)
        acc[mt][nt] = __builtin_amdgcn_mfma_f32_16x16x32_bf16(af[mt], bf[nt], acc[mt][nt], 0, 0, 0);
    __syncthreads();
  }

#pragma unroll
  for (int nt = 0; nt < 4; nt++) {
    const int gn = n0 + wn * 64 + nt * 16 + l15;
    if (NCLIP && gn >= N) continue;
    const float bvv = (EPI == 4) ? 0.0f : bias[gn];
#pragma unroll
    for (int mt = 0; mt < 4; mt++) {
#pragma unroll
      for (int i = 0; i < 4; i++) {
        const int gm = m0 + wm * 64 + mt * 16 + quad * 4 + i;
        const size_t oidx = (size_t)gm * N + gn;
        float v = acc[mt][nt][i] + bvv;
        if (EPI == 2) {
          float xg = v;
          v = 0.5f * xg * (1.0f + tanhf(0.7978845608028654f * (xg + 0.044715f * xg * xg * xg)));
        }
        if (EPI == 3) v += resid[oidx];
        if (EPI == 1 || EPI == 3 || EPI == 4) ((float*)out)[oidx] = v;
        else ((u16*)out)[oidx] = f2bf(v);
      }
    }
  }
}

template<int EPI>
__global__ __launch_bounds__(256) void gemm128(
    const u16* __restrict__ A, int lda, int aoff,
    const u16* __restrict__ BT, const float* __restrict__ bias,
    const float* __restrict__ resid, void* __restrict__ out,
    int M, int N, int K) {
  __shared__ __align__(16) u16 As[128 * 32];
  __shared__ __align__(16) u16 Bs[128 * 32];
  g128_body<EPI, false>(As, Bs, A, lda, aoff, BT, bias, resid, out,
                        N, K, K, blockIdx.x * 128, blockIdx.y * 128, 0);
}

// split-K (blockIdx.z = K chunk) -> f32 partials, no bias
__global__ __launch_bounds__(256) void gemm128_splitk(
    const u16* __restrict__ A, int lda, const u16* __restrict__ BT,
    float* __restrict__ part, int N, int Kfull, int Klen) {
  __shared__ __align__(16) u16 As[128 * 32];
  __shared__ __align__(16) u16 Bs[128 * 32];
  const int z = blockIdx.z;
  g128_body<4, false>(As, Bs, A, lda, 0, BT, nullptr, nullptr,
                      part + (size_t)z * 4096 * N,
                      N, Kfull, Klen, blockIdx.x * 128, blockIdx.y * 128, z * Klen);
}

// out = h + bias + part[0..3]   (f2 epilogue, split-K=4)
__global__ __launch_bounds__(256) void f2_reduce(
    const float* __restrict__ part, const float* __restrict__ h,
    const float* __restrict__ bias, float* __restrict__ out) {
  const size_t base = (size_t)blockIdx.x * 1024;
  const size_t PS = (size_t)4096 * 1024;
#pragma unroll
  for (int i = 0; i < 4; i++) {
    const int col = threadIdx.x + 256 * i;
    out[base + col] = h[base + col] + bias[col] + part[base + col] +
                      part[PS + base + col] + part[2 * PS + base + col] +
                      part[3 * PS + base + col];
  }
}

// ---------------------------------------------------------------------------
// Fused qr/kr/kv/q projections, all reading comp. grid (32, 33).
// ---------------------------------------------------------------------------
__global__ __launch_bounds__(256) void proj_fused(
    const u16* __restrict__ comp,
    const u16* __restrict__ WT_qr, const float* __restrict__ b_qr, float* __restrict__ qr_pre,
    const u16* __restrict__ WT_kr, const float* __restrict__ b_kr, float* __restrict__ kr_pre,
    const u16* __restrict__ WT_kv, const float* __restrict__ b_kv, u16* __restrict__ kvbuf,
    const u16* __restrict__ WT_q, const float* __restrict__ b_q, u16* __restrict__ qbuf) {
  __shared__ __align__(16) u16 As[128 * 32];
  __shared__ __align__(16) u16 Bs[128 * 32];
  const int m0 = blockIdx.x * 128;
  const int ny = blockIdx.y;
  if (ny < 8)
    g128_body<1, false>(As, Bs, comp, 1024, 0, WT_qr, b_qr, nullptr, qr_pre, 1024, 1024, 1024, m0, ny * 128, 0);
  else if (ny == 8)
    g128_body<1, true>(As, Bs, comp, 1024, 0, WT_kr, b_kr, nullptr, kr_pre, 64, 1024, 1024, m0, 0, 0);
  else if (ny < 25)
    g128_body<0, false>(As, Bs, comp, 1024, 0, WT_kv, b_kv, nullptr, kvbuf, 2048, 512, 512, m0, (ny - 9) * 128, 0);
  else
    g128_body<0, false>(As, Bs, comp, 1024, 512, WT_q, b_q, nullptr, qbuf, 1024, 512, 512, m0, (ny - 25) * 128, 0);
}

// ---------------------------------------------------------------------------
// RoPE + head assembly: Qf/Kf [B,NH,T,128] bf16
// ---------------------------------------------------------------------------
__global__ __launch_bounds__(256) void rope_build(
    const u16* __restrict__ qb, const float* __restrict__ qr_pre,
    const u16* __restrict__ kvb, const float* __restrict__ kr_pre,
    u16* __restrict__ Qf, u16* __restrict__ Kf) {
  const int bt = blockIdx.x;
  const int b = bt >> 10, t = bt & 1023;
  const float freq = (float)(t + 1);
  for (int idx = threadIdx.x; idx < 2048; idx += 256) {
    const int h = idx >> 7, d = idx & 127;
    const size_t dst = (((size_t)(b * 16 + h)) * T_ + t) * 128 + d;
    u16 qv, kvv;
    if (d < 64) {
      qv = qb[(size_t)bt * C_ + h * 64 + d];
      kvv = kvb[(size_t)bt * 2048 + h * 64 + d];
    } else {
      const int dd = d - 64;
      {
        const int g = h * 64 + dd;
        const int p = g >> 1;
        const float theta = __expf(-(float)(2 * p) * (9.210340372f / 1024.0f));
        float s, c;
        sincosf(freq * theta, &s, &c);
        const float x0 = qr_pre[(size_t)bt * 1024 + (p << 1)];
        const float x1 = qr_pre[(size_t)bt * 1024 + (p << 1) + 1];
        qv = f2bf((g & 1) ? (x1 * c + x0 * s) : (x0 * c - x1 * s));
      }
      {
        const int p = dd >> 1;
        const float theta = __expf(-(float)(2 * p) * (9.210340372f / 64.0f));
        float s, c;
        sincosf(freq * theta, &s, &c);
        const float x0 = kr_pre[(size_t)bt * 64 + (p << 1)];
        const float x1 = kr_pre[(size_t)bt * 64 + (p << 1) + 1];
        kvv = f2bf((dd & 1) ? (x1 * c + x0 * s) : (x0 * c - x1 * s));
      }
    }
    Qf[dst] = qv;
    Kf[dst] = kvv;
  }
}

// ---------------------------------------------------------------------------
// V transpose: kvbuf V-half [B,T,NH,64] -> Vf [B,NH,64,T]
// ---------------------------------------------------------------------------
__global__ __launch_bounds__(256) void vtrans_kernel(
    const u16* __restrict__ kvb, u16* __restrict__ Vf) {
  __shared__ u16 tile[64][72];
  const int bh = blockIdx.x, t0 = blockIdx.y * 64;
  const int b = bh >> 4, h = bh & 15;
  const int r = threadIdx.x >> 2, seg = (threadIdx.x & 3) * 16;
  const u16* src = &kvb[((size_t)(b * 1024) + t0 + r) * 2048 + 1024 + h * 64 + seg];
  *(uint4*)&tile[r][seg] = *(const uint4*)src;
  *(uint4*)&tile[r][seg + 8] = *(const uint4*)(src + 8);
  __syncthreads();
  const int d = threadIdx.x >> 2, ts = (threadIdx.x & 3) * 16;
  u16 tmp[16];
#pragma unroll
  for (int j = 0; j < 16; j++) tmp[j] = tile[ts + j][d];
  u16* dst = &Vf[((size_t)bh * 64 + d) * 1024 + t0 + ts];
  *(uint4*)dst = *(uint4*)tmp;
  *(uint4*)(dst + 8) = *(uint4*)(tmp + 8);
}

// ---------------------------------------------------------------------------
// MFMA flash attention v3: balanced q-tile pairing.
// Block = (b, h, j) with j in 0..7, processes q-tiles {15-j, j} -> exactly
// 17 K-tile iterations per block (uniform). 512 blocks, 256 thr = 4 waves.
// ---------------------------------------------------------------------------
#define KSTR 136
#define VSTR 72

__device__ __forceinline__ void attn_tile(
    u16* Ks, u16* Vt, u16* Ps,
    const u16* __restrict__ Qf, const u16* __restrict__ Kf,
    const u16* __restrict__ Vf, u16* __restrict__ attn_o,
    int b, int h, int qt) {
  const int tid = threadIdx.x;
  const int wave = tid >> 6, lane = tid & 63;
  const int quad = lane >> 4, l15 = lane & 15;
  const int q0 = qt * 64;
  const size_t bh = (size_t)(b * 16 + h);

  bf16x8 qfrag[4];
  {
    const u16* qb = &Qf[(bh * T_ + q0 + wave * 16 + l15) * 128 + quad * 8];
#pragma unroll
    for (int kc = 0; kc < 4; kc++) qfrag[kc] = *(const bf16x8*)(qb + kc * 32);
  }

  f32x4 acc_o[4] = {};
  float m_i[4], l_i[4];
#pragma unroll
  for (int i = 0; i < 4; i++) { m_i[i] = -3.0e38f; l_i[i] = 0.0f; }

  const int kr_ = tid >> 3, kcs = (tid & 7) * 16;
  const int vd = tid >> 2, vts = (tid & 3) * 16;
  u16* Pw = Ps + wave * 16 * VSTR;

  for (int kt = 0; kt <= qt; kt++) {
    __syncthreads();
    {
      const u16* s0 = &Kf[(bh * T_ + kt * 64 + kr_) * 128 + kcs];
      const u16* s1 = s0 + 32 * 128;
      *(uint4*)&Ks[kr_ * KSTR + kcs] = *(const uint4*)s0;
      *(uint4*)&Ks[kr_ * KSTR + kcs + 8] = *(const uint4*)(s0 + 8);
      *(uint4*)&Ks[(kr_ + 32) * KSTR + kcs] = *(const uint4*)s1;
      *(uint4*)&Ks[(kr_ + 32) * KSTR + kcs + 8] = *(const uint4*)(s1 + 8);
      const u16* vs = &Vf[(bh * 64 + vd) * 1024 + kt * 64 + vts];
      *(uint4*)&Vt[vd * VSTR + vts] = *(const uint4*)vs;
      *(uint4*)&Vt[vd * VSTR + vts + 8] = *(const uint4*)(vs + 8);
    }
    __syncthreads();

    f32x4 acc_s[4] = {};
#pragma unroll
    for (int kc = 0; kc < 4; kc++) {
#pragma unroll
      for (int ng = 0; ng < 4; ng++) {
        bf16x8 bb = *(const bf16x8*)&Ks[(ng * 16 + l15) * KSTR + kc * 32 + quad * 8];
        acc_s[ng] = __builtin_amdgcn_mfma_f32_16x16x32_bf16(qfrag[kc], bb, acc_s[ng], 0, 0, 0);
      }
    }

    float sv[4][4];
#pragma unroll
    for (int ng = 0; ng < 4; ng++)
#pragma unroll
      for (int i = 0; i < 4; i++) {
        float s = acc_s[ng][i] * 0.125f;
        if (kt == qt && (ng * 16 + l15) > (wave * 16 + quad * 4 + i)) s = -3.0e38f;
        sv[ng][i] = s;
      }

    float alpha[4], mx[4];
#pragma unroll
    for (int i = 0; i < 4; i++) {
      float m = fmaxf(fmaxf(sv[0][i], sv[1][i]), fmaxf(sv[2][i], sv[3][i]));
#pragma unroll
      for (int off = 1; off < 16; off <<= 1) m = fmaxf(m, __shfl_xor(m, off, 64));
      float mn = fmaxf(m_i[i], m);
      alpha[i] = __expf(m_i[i] - mn);
      m_i[i] = mn;
      mx[i] = mn;
    }
    float rs[4] = {0.f, 0.f, 0.f, 0.f};
#pragma unroll
    for (int ng = 0; ng < 4; ng++)
#pragma unroll
      for (int i = 0; i < 4; i++) {
        float p = __expf(sv[ng][i] - mx[i]);
        rs[i] += p;
        Pw[(quad * 4 + i) * VSTR + ng * 16 + l15] = f2bf(p);
      }
#pragma unroll
    for (int i = 0; i < 4; i++) {
      float r = rs[i];
#pragma unroll
      for (int off = 1; off < 16; off <<= 1) r += __shfl_xor(r, off, 64);
      l_i[i] = l_i[i] * alpha[i] + r;
    }

#pragma unroll
    for (int ng = 0; ng < 4; ng++)
#pragma unroll
      for (int i = 0; i < 4; i++) acc_o[ng][i] *= alpha[i];
#pragma unroll
    for (int kc = 0; kc < 2; kc++) {
      bf16x8 a = *(const bf16x8*)&Pw[l15 * VSTR + kc * 32 + quad * 8];
#pragma unroll
      for (int ng = 0; ng < 4; ng++) {
        bf16x8 bb = *(const bf16x8*)&Vt[(ng * 16 + l15) * VSTR + kc * 32 + quad * 8];
        acc_o[ng] = __builtin_amdgcn_mfma_f32_16x16x32_bf16(a, bb, acc_o[ng], 0, 0, 0);
      }
    }
  }

  float linv[4];
#pragma unroll
  for (int i = 0; i < 4; i++) linv[i] = 1.0f / l_i[i];
#pragma unroll
  for (int ng = 0; ng < 4; ng++)
#pragma unroll
    for (int i = 0; i < 4; i++) {
      const int qrow = q0 + wave * 16 + quad * 4 + i;
      attn_o[((size_t)(b * T_) + qrow) * C_ + h * 64 + ng * 16 + l15] =
          f2bf(acc_o[ng][i] * linv[i]);
    }
}

__global__ __launch_bounds__(256) void attn_mfma(
    const u16* __restrict__ Qf, const u16* __restrict__ Kf,
    const u16* __restrict__ Vf, u16* __restrict__ attn_o) {
  __shared__ __align__(16) u16 Ks[64 * KSTR];
  __shared__ __align__(16) u16 Vt[64 * VSTR];
  __shared__ __align__(16) u16 Ps[4 * 16 * VSTR];
  const int j = blockIdx.x & 7;
  const int h = (blockIdx.x >> 3) & 15;
  const int b = blockIdx.x >> 7;
  attn_tile(Ks, Vt, Ps, Qf, Kf, Vf, attn_o, b, h, 15 - j);  // heavy first
  attn_tile(Ks, Vt, Ps, Qf, Kf, Vf, attn_o, b, h, j);
}

// ---------------------------------------------------------------------------
extern "C" void kernel_launch(void* const* d_in, const int* in_sizes, int n_in,
                              void* d_out, int out_size, void* d_ws, size_t ws_size,
                              hipStream_t stream) {
  const float* x = (const float*)d_in[0];
  const float* rms1 = (const float*)d_in[1];
  const float* rms2 = (const float*)d_in[2];
  const float* W_dkv = (const float*)d_in[3];
  const float* b_dkv = (const float*)d_in[4];
  const float* W_kr = (const float*)d_in[5];
  const float* b_kr = (const float*)d_in[6];
  const float* W_qr = (const float*)d_in[7];
  const float* b_qr = (const float*)d_in[8];
  const float* W_kv = (const float*)d_in[9];
  const float* b_kv = (const float*)d_in[10];
  const float* W_q = (const float*)d_in[11];
  const float* b_q = (const float*)d_in[12];
  const float* W_o = (const float*)d_in[13];
  const float* b_o = (const float*)d_in[14];
  const float* W_f1 = (const float*)d_in[15];
  const float* b_f1 = (const float*)d_in[16];
  const float* W_f2 = (const float*)d_in[17];
  const float* b_f2 = (const float*)d_in[18];
  float* out = (float*)d_out;

  char* ws = (char*)d_ws;
  size_t off = 0;
  auto alloc = [&](size_t bytes) -> void* {
    void* p = ws + off;
    off += (bytes + 255) & ~(size_t)255;
    return p;
  };
  u16* WT_dkv = (u16*)alloc((size_t)1024 * 1024 * 2);
  u16* WT_kr  = (u16*)alloc((size_t)128 * 1024 * 2);  // 64 real rows + 64 pad
  u16* WT_qr  = (u16*)alloc((size_t)1024 * 1024 * 2);
  u16* WT_kv  = (u16*)alloc((size_t)2048 * 512 * 2);
  u16* WT_q   = (u16*)alloc((size_t)1024 * 512 * 2);
  u16* WT_o   = (u16*)alloc((size_t)1024 * 1024 * 2);
  u16* WT_f1  = (u16*)alloc((size_t)4096 * 1024 * 2);
  u16* WT_f2  = (u16*)alloc((size_t)1024 * 4096 * 2);
  u16* xn1    = (u16*)alloc((size_t)4096 * 1024 * 2);
  u16* comp   = (u16*)alloc((size_t)4096 * 1024 * 2);
  float* kr_pre = (float*)alloc((size_t)4096 * 64 * 4);
  float* qr_pre = (float*)alloc((size_t)4096 * 1024 * 4);
  u16* kvbuf  = (u16*)alloc((size_t)4096 * 2048 * 2);
  u16* qbuf   = (u16*)alloc((size_t)4096 * 1024 * 2);
  // Qf..pad16 form a contiguous 64 MB region reused as f2 split-K partials
  u16* Qf     = (u16*)alloc((size_t)64 * 1024 * 128 * 2);   // 16 MB
  u16* Kf     = (u16*)alloc((size_t)64 * 1024 * 128 * 2);   // 16 MB
  u16* Vf     = (u16*)alloc((size_t)64 * 64 * 1024 * 2);    // 8 MB
  u16* attn_o = (u16*)alloc((size_t)4096 * 1024 * 2);       // 8 MB
  alloc((size_t)4096 * 1024 * 4);                           // 16 MB pad
  float* hbuf = (float*)alloc((size_t)4096 * 1024 * 4);
  u16* hn     = (u16*)alloc((size_t)4096 * 1024 * 2);
  u16* hid    = (u16*)alloc((size_t)4096 * 4096 * 2);
  float* partial = (float*)Qf;  // 4 x 16 MB, all dead by f2 time

  // one dispatch for all 8 weight transposes
  TransArgs ta;
  const float* srcs[8] = {W_dkv, W_kr, W_qr, W_kv, W_q, W_o, W_f1, W_f2};
  u16* dsts[8] = {WT_dkv, WT_kr, WT_qr, WT_kv, WT_q, WT_o, WT_f1, WT_f2};
  const int Rs[8] = {1024, 1024, 1024, 512, 512, 1024, 1024, 4096};
  const int Cs[8] = {1024, 64, 1024, 2048, 1024, 1024, 4096, 1024};
  int acc_t = 0;
  for (int i = 0; i < 8; i++) {
    ta.src[i] = srcs[i]; ta.dst[i] = dsts[i]; ta.R[i] = Rs[i]; ta.C[i] = Cs[i];
    ta.base[i] = acc_t;
    acc_t += (Rs[i] >> 5) * (Cs[i] >> 5);
  }
  ta.base[8] = acc_t;
  transpose_all<<<acc_t, dim3(32, 8), 0, stream>>>(ta);

  rmsnorm_kernel<<<4096, 256, 0, stream>>>(x, rms1, xn1);

  gemm128<0><<<dim3(32, 8), 256, 0, stream>>>(xn1, 1024, 0, WT_dkv, b_dkv, nullptr, comp, 4096, 1024, 1024);

  proj_fused<<<dim3(32, 33), 256, 0, stream>>>(comp,
      WT_qr, b_qr, qr_pre, WT_kr, b_kr, kr_pre,
      WT_kv, b_kv, kvbuf, WT_q, b_q, qbuf);

  rope_build<<<4096, 256, 0, stream>>>(qbuf, qr_pre, kvbuf, kr_pre, Qf, Kf);
  vtrans_kernel<<<dim3(64, 16), 256, 0, stream>>>(kvbuf, Vf);

  attn_mfma<<<B_ * NH_ * 8, 256, 0, stream>>>(Qf, Kf, Vf, attn_o);

  gemm128<3><<<dim3(32, 8), 256, 0, stream>>>(attn_o, 1024, 0, WT_o, b_o, x, hbuf, 4096, 1024, 1024);

  rmsnorm_kernel<<<4096, 256, 0, stream>>>(hbuf, rms2, hn);

  gemm128<2><<<dim3(32, 32), 256, 0, stream>>>(hn, 1024, 0, WT_f1, b_f1, nullptr, hid, 4096, 4096, 1024);

  gemm128_splitk<<<dim3(32, 8, 4), 256, 0, stream>>>(hid, 4096, WT_f2, partial, 1024, 4096, 1024);
  f2_reduce<<<4096, 256, 0, stream>>>(partial, hbuf, b_f2, out);
}

// Round 7
// 444.994 us; speedup vs baseline: 1.3121x; 1.0596x over previous
//
#include <hip/hip_runtime.h>

typedef unsigned int u32;
typedef unsigned short u16;
typedef __bf16 bf16x8 __attribute__((ext_vector_type(8)));
typedef float f32x4 __attribute__((ext_vector_type(4)));

#define B_ 4
#define T_ 1024
#define C_ 1024
#define NH_ 16
#define L_ 512
#define DHR_ 64
#define FF_ 4096

typedef __attribute__((address_space(3))) u32 as3_u32;
typedef __attribute__((address_space(1))) u32 as1_u32;

__device__ __forceinline__ void gld16(const u16* g, u16* l) {
  __builtin_amdgcn_global_load_lds((const as1_u32*)g, (as3_u32*)l, 16, 0, 0);
}

__device__ __forceinline__ float bf2f(u16 u) {
  union { u32 i; float f; } v; v.i = ((u32)u) << 16; return v.f;
}
__device__ __forceinline__ u16 f2bf(float f) {
  union { float f; u32 i; } v; v.f = f;
  u32 r = (v.i + 0x7FFFu + ((v.i >> 16) & 1u)) >> 16;
  return (u16)r;
}

// ---------------------------------------------------------------------------
// Fused pre-pass: 8 weight transposes (f32 [R,C] -> bf16 [C,R]) + rmsnorm1
// as tail blocks. Block (32,8).
// ---------------------------------------------------------------------------
struct TransArgs {
  const float* src[8];
  u16* dst[8];
  int R[8], C[8];
  int base[9];
  const float* x;
  const float* rmsw;
  u16* xn;
};

__global__ void pre_all(TransArgs ta) {
  const int bid = blockIdx.x;
  if (bid >= ta.base[8]) {  // rmsnorm row
    const int row = bid - ta.base[8];
    const int tid = threadIdx.y * 32 + threadIdx.x;
    const float* xp = ta.x + (size_t)row * C_;
    float v[4];
#pragma unroll
    for (int i = 0; i < 4; i++) v[i] = xp[tid + 256 * i];
    float ss = v[0] * v[0] + v[1] * v[1] + v[2] * v[2] + v[3] * v[3];
#pragma unroll
    for (int o = 32; o > 0; o >>= 1) ss += __shfl_down(ss, o, 64);
    __shared__ float red[4];
    if ((tid & 63) == 0) red[tid >> 6] = ss;
    __syncthreads();
    ss = red[0] + red[1] + red[2] + red[3];
    float scale = rsqrtf(ss * (1.0f / 1024.0f) + 1e-6f);
    u16* op = ta.xn + (size_t)row * C_;
#pragma unroll
    for (int i = 0; i < 4; i++)
      op[tid + 256 * i] = f2bf(v[i] * scale * ta.rmsw[tid + 256 * i]);
    return;
  }
  __shared__ float tile[32][33];
  int w = 0;
#pragma unroll
  for (int i = 1; i < 8; i++) w += (bid >= ta.base[i]);
  const int local = bid - ta.base[w];
  const int R = ta.R[w], C = ta.C[w];
  const int ctiles = C >> 5;
  const int bx = (local % ctiles) * 32;
  const int by = (local / ctiles) * 32;
  const float* in = ta.src[w];
  u16* outp = ta.dst[w];
  const int tx = threadIdx.x, ty = threadIdx.y;
  for (int i = ty; i < 32; i += 8)
    tile[i][tx] = in[(size_t)(by + i) * C + bx + tx];
  __syncthreads();
  for (int i = ty; i < 32; i += 8)
    outp[(size_t)(bx + i) * R + by + tx] = f2bf(tile[tx][i]);
}

// ---------------------------------------------------------------------------
// RMSNorm (standalone, for h): f32 in, f32 weight, bf16 out
// ---------------------------------------------------------------------------
__global__ __launch_bounds__(256) void rmsnorm_kernel(const float* __restrict__ xin,
                                                      const float* __restrict__ w,
                                                      u16* __restrict__ outp) {
  const int row = blockIdx.x;
  const int tid = threadIdx.x;
  const float* xp = xin + (size_t)row * C_;
  float v[4];
#pragma unroll
  for (int i = 0; i < 4; i++) v[i] = xp[tid + 256 * i];
  float ss = v[0] * v[0] + v[1] * v[1] + v[2] * v[2] + v[3] * v[3];
#pragma unroll
  for (int o = 32; o > 0; o >>= 1) ss += __shfl_down(ss, o, 64);
  __shared__ float red[4];
  if ((tid & 63) == 0) red[tid >> 6] = ss;
  __syncthreads();
  ss = red[0] + red[1] + red[2] + red[3];
  float scale = rsqrtf(ss * (1.0f / 1024.0f) + 1e-6f);
  u16* op = outp + (size_t)row * C_;
#pragma unroll
  for (int i = 0; i < 4; i++)
    op[tid + 256 * i] = f2bf(v[i] * scale * w[tid + 256 * i]);
}

// ---------------------------------------------------------------------------
// Templated MFMA GEMM body (m97 structure). Block tile 128 x (NT*32).
// NT=4 -> 128x128, NT=2 -> 128x64 (2x the blocks for small-grid shapes).
// EPI: 0 bf16 | 1 f32 | 2 bf16+gelu | 3 f32+f32 resid | 4 f32 partial.
// ---------------------------------------------------------------------------
template<int EPI, bool NCLIP, int NT>
__device__ __forceinline__ void g_body(
    u16* As, u16* Bs,
    const u16* __restrict__ A, int lda, int aoff,
    const u16* __restrict__ BT, const float* __restrict__ bias,
    const float* __restrict__ resid, void* __restrict__ out,
    int N, int Kfull, int Klen, int m0, int n0, int koff) {
  const int tid = threadIdx.x;
  const int wave = tid >> 6, lane = tid & 63;
  const int wm = wave >> 1, wn = wave & 1;
  const int quad = lane >> 4, l15 = lane & 15;
  const int row = tid >> 2, seg = tid & 3;

  const u16* aP = A + (size_t)(m0 + row) * lda + aoff + koff + seg * 8;
  const u16* bP = BT + (size_t)(n0 + row) * Kfull + koff + seg * 8;
  u16* aL = As + row * 32 + seg * 8;
  u16* bL = Bs + row * 32 + seg * 8;
  const size_t aStep = (size_t)64 * lda;
  const size_t bStep = (size_t)64 * Kfull;

  f32x4 acc[4][NT] = {};

  for (int k0 = 0; k0 < Klen; k0 += 32) {
    gld16(aP + k0, aL);
    gld16(aP + k0 + aStep, aL + 64 * 32);
    gld16(bP + k0, bL);
    if (NT == 4) gld16(bP + k0 + bStep, bL + 64 * 32);
    __syncthreads();
    bf16x8 af[4], bfr[NT];
#pragma unroll
    for (int mt = 0; mt < 4; mt++)
      af[mt] = *(const bf16x8*)&As[(wm * 64 + mt * 16 + l15) * 32 + quad * 8];
#pragma unroll
    for (int nt = 0; nt < NT; nt++)
      bfr[nt] = *(const bf16x8*)&Bs[(wn * (NT * 16) + nt * 16 + l15) * 32 + quad * 8];
#pragma unroll
    for (int mt = 0; mt < 4; mt++)
#pragma unroll
      for (int nt = 0; nt < NT; nt++)
        acc[mt][nt] = __builtin_amdgcn_mfma_f32_16x16x32_bf16(af[mt], bfr[nt], acc[mt][nt], 0, 0, 0);
    __syncthreads();
  }

  float bvv[NT];
#pragma unroll
  for (int nt = 0; nt < NT; nt++) {
    const int gn = n0 + wn * (NT * 16) + nt * 16 + l15;
    bvv[nt] = (EPI == 4) ? 0.0f : ((NCLIP && gn >= N) ? 0.0f : bias[gn]);
  }
  // store order: nt innermost so adjacent 32B segments issue back-to-back
#pragma unroll
  for (int mt = 0; mt < 4; mt++) {
#pragma unroll
    for (int i = 0; i < 4; i++) {
      const int gm = m0 + wm * 64 + mt * 16 + quad * 4 + i;
      const size_t rowb = (size_t)gm * N;
#pragma unroll
      for (int nt = 0; nt < NT; nt++) {
        const int gn = n0 + wn * (NT * 16) + nt * 16 + l15;
        if (NCLIP && gn >= N) continue;
        const size_t oidx = rowb + gn;
        float v = acc[mt][nt][i] + bvv[nt];
        if (EPI == 2) {  // fast tanh-gelu: x*t/(t+1), t=e^{2y}
          float y = 0.7978845608028654f * (v + 0.044715f * v * v * v);
          float t = __expf(fminf(2.0f * y, 80.0f));
          v = v * t / (t + 1.0f);
        }
        if (EPI == 3) v += resid[oidx];
        if (EPI == 1 || EPI == 3 || EPI == 4) ((float*)out)[oidx] = v;
        else ((u16*)out)[oidx] = f2bf(v);
      }
    }
  }
}

template<int EPI, int NT>
__global__ __launch_bounds__(256) void gemmN(
    const u16* __restrict__ A, int lda, int aoff,
    const u16* __restrict__ BT, const float* __restrict__ bias,
    const float* __restrict__ resid, void* __restrict__ out,
    int N, int K) {
  __shared__ __align__(16) u16 As[128 * 32];
  __shared__ __align__(16) u16 Bs[NT * 32 * 32];
  g_body<EPI, false, NT>(As, Bs, A, lda, aoff, BT, bias, resid, out,
                         N, K, K, blockIdx.x * 128, blockIdx.y * (NT * 32), 0);
}

// split-K (blockIdx.z = K chunk) -> f32 partials, no bias
__global__ __launch_bounds__(256) void gemm128_splitk(
    const u16* __restrict__ A, int lda, const u16* __restrict__ BT,
    float* __restrict__ part, int N, int Kfull, int Klen) {
  __shared__ __align__(16) u16 As[128 * 32];
  __shared__ __align__(16) u16 Bs[128 * 32];
  const int z = blockIdx.z;
  g_body<4, false, 4>(As, Bs, A, lda, 0, BT, nullptr, nullptr,
                      part + (size_t)z * 4096 * N,
                      N, Kfull, Klen, blockIdx.x * 128, blockIdx.y * 128, z * Klen);
}

// out = h + bias + part[0..3]
__global__ __launch_bounds__(256) void f2_reduce(
    const float* __restrict__ part, const float* __restrict__ h,
    const float* __restrict__ bias, float* __restrict__ out) {
  const size_t base = (size_t)blockIdx.x * 1024;
  const size_t PS = (size_t)4096 * 1024;
#pragma unroll
  for (int i = 0; i < 4; i++) {
    const int col = threadIdx.x + 256 * i;
    out[base + col] = h[base + col] + bias[col] + part[base + col] +
                      part[PS + base + col] + part[2 * PS + base + col] +
                      part[3 * PS + base + col];
  }
}

// ---------------------------------------------------------------------------
// Fused qr/kr/kv/q projections, all reading comp. grid (32, 33).
// ---------------------------------------------------------------------------
__global__ __launch_bounds__(256) void proj_fused(
    const u16* __restrict__ comp,
    const u16* __restrict__ WT_qr, const float* __restrict__ b_qr, float* __restrict__ qr_pre,
    const u16* __restrict__ WT_kr, const float* __restrict__ b_kr, float* __restrict__ kr_pre,
    const u16* __restrict__ WT_kv, const float* __restrict__ b_kv, u16* __restrict__ kvbuf,
    const u16* __restrict__ WT_q, const float* __restrict__ b_q, u16* __restrict__ qbuf) {
  __shared__ __align__(16) u16 As[128 * 32];
  __shared__ __align__(16) u16 Bs[128 * 32];
  const int m0 = blockIdx.x * 128;
  const int ny = blockIdx.y;
  if (ny < 8)
    g_body<1, false, 4>(As, Bs, comp, 1024, 0, WT_qr, b_qr, nullptr, qr_pre, 1024, 1024, 1024, m0, ny * 128, 0);
  else if (ny == 8)
    g_body<1, true, 4>(As, Bs, comp, 1024, 0, WT_kr, b_kr, nullptr, kr_pre, 64, 1024, 1024, m0, 0, 0);
  else if (ny < 25)
    g_body<0, false, 4>(As, Bs, comp, 1024, 0, WT_kv, b_kv, nullptr, kvbuf, 2048, 512, 512, m0, (ny - 9) * 128, 0);
  else
    g_body<0, false, 4>(As, Bs, comp, 1024, 512, WT_q, b_q, nullptr, qbuf, 1024, 512, 512, m0, (ny - 25) * 128, 0);
}

// ---------------------------------------------------------------------------
// Fused RoPE head-assembly (blocks 0..4095) + V transpose (blocks 4096..5119)
// ---------------------------------------------------------------------------
__global__ __launch_bounds__(256) void rope_vtrans(
    const u16* __restrict__ qb, const float* __restrict__ qr_pre,
    const u16* __restrict__ kvb, const float* __restrict__ kr_pre,
    u16* __restrict__ Qf, u16* __restrict__ Kf, u16* __restrict__ Vf) {
  __shared__ u16 tile[64][72];
  if (blockIdx.x >= 4096) {  // vtrans
    const int bid2 = blockIdx.x - 4096;
    const int bh = bid2 & 63, t0 = (bid2 >> 6) * 64;
    const int b = bh >> 4, h = bh & 15;
    const int r = threadIdx.x >> 2, seg = (threadIdx.x & 3) * 16;
    const u16* src = &kvb[((size_t)(b * 1024) + t0 + r) * 2048 + 1024 + h * 64 + seg];
    *(uint4*)&tile[r][seg] = *(const uint4*)src;
    *(uint4*)&tile[r][seg + 8] = *(const uint4*)(src + 8);
    __syncthreads();
    const int d = threadIdx.x >> 2, ts = (threadIdx.x & 3) * 16;
    u16 tmp[16];
#pragma unroll
    for (int j = 0; j < 16; j++) tmp[j] = tile[ts + j][d];
    u16* dst = &Vf[((size_t)bh * 64 + d) * 1024 + t0 + ts];
    *(uint4*)dst = *(uint4*)tmp;
    *(uint4*)(dst + 8) = *(uint4*)(tmp + 8);
    return;
  }
  const int bt = blockIdx.x;
  const int b = bt >> 10, t = bt & 1023;
  const float freq = (float)(t + 1);
  for (int idx = threadIdx.x; idx < 2048; idx += 256) {
    const int h = idx >> 7, d = idx & 127;
    const size_t dst = (((size_t)(b * 16 + h)) * T_ + t) * 128 + d;
    u16 qv, kvv;
    if (d < 64) {
      qv = qb[(size_t)bt * C_ + h * 64 + d];
      kvv = kvb[(size_t)bt * 2048 + h * 64 + d];
    } else {
      const int dd = d - 64;
      {
        const int g = h * 64 + dd;
        const int p = g >> 1;
        const float theta = __expf(-(float)(2 * p) * (9.210340372f / 1024.0f));
        float s, c;
        sincosf(freq * theta, &s, &c);
        const float x0 = qr_pre[(size_t)bt * 1024 + (p << 1)];
        const float x1 = qr_pre[(size_t)bt * 1024 + (p << 1) + 1];
        qv = f2bf((g & 1) ? (x1 * c + x0 * s) : (x0 * c - x1 * s));
      }
      {
        const int p = dd >> 1;
        const float theta = __expf(-(float)(2 * p) * (9.210340372f / 64.0f));
        float s, c;
        sincosf(freq * theta, &s, &c);
        const float x0 = kr_pre[(size_t)bt * 64 + (p << 1)];
        const float x1 = kr_pre[(size_t)bt * 64 + (p << 1) + 1];
        kvv = f2bf((dd & 1) ? (x1 * c + x0 * s) : (x0 * c - x1 * s));
      }
    }
    Qf[dst] = qv;
    Kf[dst] = kvv;
  }
}

// ---------------------------------------------------------------------------
// MFMA flash attention (balanced pairing, unchanged from round 6)
// ---------------------------------------------------------------------------
#define KSTR 136
#define VSTR 72

__device__ __forceinline__ void attn_tile(
    u16* Ks, u16* Vt, u16* Ps,
    const u16* __restrict__ Qf, const u16* __restrict__ Kf,
    const u16* __restrict__ Vf, u16* __restrict__ attn_o,
    int b, int h, int qt) {
  const int tid = threadIdx.x;
  const int wave = tid >> 6, lane = tid & 63;
  const int quad = lane >> 4, l15 = lane & 15;
  const int q0 = qt * 64;
  const size_t bh = (size_t)(b * 16 + h);

  bf16x8 qfrag[4];
  {
    const u16* qb = &Qf[(bh * T_ + q0 + wave * 16 + l15) * 128 + quad * 8];
#pragma unroll
    for (int kc = 0; kc < 4; kc++) qfrag[kc] = *(const bf16x8*)(qb + kc * 32);
  }

  f32x4 acc_o[4] = {};
  float m_i[4], l_i[4];
#pragma unroll
  for (int i = 0; i < 4; i++) { m_i[i] = -3.0e38f; l_i[i] = 0.0f; }

  const int kr_ = tid >> 3, kcs = (tid & 7) * 16;
  const int vd = tid >> 2, vts = (tid & 3) * 16;
  u16* Pw = Ps + wave * 16 * VSTR;

  for (int kt = 0; kt <= qt; kt++) {
    __syncthreads();
    {
      const u16* s0 = &Kf[(bh * T_ + kt * 64 + kr_) * 128 + kcs];
      const u16* s1 = s0 + 32 * 128;
      *(uint4*)&Ks[kr_ * KSTR + kcs] = *(const uint4*)s0;
      *(uint4*)&Ks[kr_ * KSTR + kcs + 8] = *(const uint4*)(s0 + 8);
      *(uint4*)&Ks[(kr_ + 32) * KSTR + kcs] = *(const uint4*)s1;
      *(uint4*)&Ks[(kr_ + 32) * KSTR + kcs + 8] = *(const uint4*)(s1 + 8);
      const u16* vs = &Vf[(bh * 64 + vd) * 1024 + kt * 64 + vts];
      *(uint4*)&Vt[vd * VSTR + vts] = *(const uint4*)vs;
      *(uint4*)&Vt[vd * VSTR + vts + 8] = *(const uint4*)(vs + 8);
    }
    __syncthreads();

    f32x4 acc_s[4] = {};
#pragma unroll
    for (int kc = 0; kc < 4; kc++) {
#pragma unroll
      for (int ng = 0; ng < 4; ng++) {
        bf16x8 bb = *(const bf16x8*)&Ks[(ng * 16 + l15) * KSTR + kc * 32 + quad * 8];
        acc_s[ng] = __builtin_amdgcn_mfma_f32_16x16x32_bf16(qfrag[kc], bb, acc_s[ng], 0, 0, 0);
      }
    }

    float sv[4][4];
#pragma unroll
    for (int ng = 0; ng < 4; ng++)
#pragma unroll
      for (int i = 0; i < 4; i++) {
        float s = acc_s[ng][i] * 0.125f;
        if (kt == qt && (ng * 16 + l15) > (wave * 16 + quad * 4 + i)) s = -3.0e38f;
        sv[ng][i] = s;
      }

    float alpha[4], mx[4];
#pragma unroll
    for (int i = 0; i < 4; i++) {
      float m = fmaxf(fmaxf(sv[0][i], sv[1][i]), fmaxf(sv[2][i], sv[3][i]));
#pragma unroll
      for (int off = 1; off < 16; off <<= 1) m = fmaxf(m, __shfl_xor(m, off, 64));
      float mn = fmaxf(m_i[i], m);
      alpha[i] = __expf(m_i[i] - mn);
      m_i[i] = mn;
      mx[i] = mn;
    }
    float rs[4] = {0.f, 0.f, 0.f, 0.f};
#pragma unroll
    for (int ng = 0; ng < 4; ng++)
#pragma unroll
      for (int i = 0; i < 4; i++) {
        float p = __expf(sv[ng][i] - mx[i]);
        rs[i] += p;
        Pw[(quad * 4 + i) * VSTR + ng * 16 + l15] = f2bf(p);
      }
#pragma unroll
    for (int i = 0; i < 4; i++) {
      float r = rs[i];
#pragma unroll
      for (int off = 1; off < 16; off <<= 1) r += __shfl_xor(r, off, 64);
      l_i[i] = l_i[i] * alpha[i] + r;
    }

#pragma unroll
    for (int ng = 0; ng < 4; ng++)
#pragma unroll
      for (int i = 0; i < 4; i++) acc_o[ng][i] *= alpha[i];
#pragma unroll
    for (int kc = 0; kc < 2; kc++) {
      bf16x8 a = *(const bf16x8*)&Pw[l15 * VSTR + kc * 32 + quad * 8];
#pragma unroll
      for (int ng = 0; ng < 4; ng++) {
        bf16x8 bb = *(const bf16x8*)&Vt[(ng * 16 + l15) * VSTR + kc * 32 + quad * 8];
        acc_o[ng] = __builtin_amdgcn_mfma_f32_16x16x32_bf16(a, bb, acc_o[ng], 0, 0, 0);
      }
    }
  }

  float linv[4];
#pragma unroll
  for (int i = 0; i < 4; i++) linv[i] = 1.0f / l_i[i];
#pragma unroll
  for (int ng = 0; ng < 4; ng++)
#pragma unroll
    for (int i = 0; i < 4; i++) {
      const int qrow = q0 + wave * 16 + quad * 4 + i;
      attn_o[((size_t)(b * T_) + qrow) * C_ + h * 64 + ng * 16 + l15] =
          f2bf(acc_o[ng][i] * linv[i]);
    }
}

__global__ __launch_bounds__(256) void attn_mfma(
    const u16* __restrict__ Qf, const u16* __restrict__ Kf,
    const u16* __restrict__ Vf, u16* __restrict__ attn_o) {
  __shared__ __align__(16) u16 Ks[64 * KSTR];
  __shared__ __align__(16) u16 Vt[64 * VSTR];
  __shared__ __align__(16) u16 Ps[4 * 16 * VSTR];
  const int j = blockIdx.x & 7;
  const int h = (blockIdx.x >> 3) & 15;
  const int b = blockIdx.x >> 7;
  attn_tile(Ks, Vt, Ps, Qf, Kf, Vf, attn_o, b, h, 15 - j);
  attn_tile(Ks, Vt, Ps, Qf, Kf, Vf, attn_o, b, h, j);
}

// ---------------------------------------------------------------------------
extern "C" void kernel_launch(void* const* d_in, const int* in_sizes, int n_in,
                              void* d_out, int out_size, void* d_ws, size_t ws_size,
                              hipStream_t stream) {
  const float* x = (const float*)d_in[0];
  const float* rms1 = (const float*)d_in[1];
  const float* rms2 = (const float*)d_in[2];
  const float* W_dkv = (const float*)d_in[3];
  const float* b_dkv = (const float*)d_in[4];
  const float* W_kr = (const float*)d_in[5];
  const float* b_kr = (const float*)d_in[6];
  const float* W_qr = (const float*)d_in[7];
  const float* b_qr = (const float*)d_in[8];
  const float* W_kv = (const float*)d_in[9];
  const float* b_kv = (const float*)d_in[10];
  const float* W_q = (const float*)d_in[11];
  const float* b_q = (const float*)d_in[12];
  const float* W_o = (const float*)d_in[13];
  const float* b_o = (const float*)d_in[14];
  const float* W_f1 = (const float*)d_in[15];
  const float* b_f1 = (const float*)d_in[16];
  const float* W_f2 = (const float*)d_in[17];
  const float* b_f2 = (const float*)d_in[18];
  float* out = (float*)d_out;

  char* ws = (char*)d_ws;
  size_t off = 0;
  auto alloc = [&](size_t bytes) -> void* {
    void* p = ws + off;
    off += (bytes + 255) & ~(size_t)255;
    return p;
  };
  u16* WT_dkv = (u16*)alloc((size_t)1024 * 1024 * 2);
  u16* WT_kr  = (u16*)alloc((size_t)128 * 1024 * 2);
  u16* WT_qr  = (u16*)alloc((size_t)1024 * 1024 * 2);
  u16* WT_kv  = (u16*)alloc((size_t)2048 * 512 * 2);
  u16* WT_q   = (u16*)alloc((size_t)1024 * 512 * 2);
  u16* WT_o   = (u16*)alloc((size_t)1024 * 1024 * 2);
  u16* WT_f1  = (u16*)alloc((size_t)4096 * 1024 * 2);
  u16* WT_f2  = (u16*)alloc((size_t)1024 * 4096 * 2);
  u16* xn1    = (u16*)alloc((size_t)4096 * 1024 * 2);
  u16* comp   = (u16*)alloc((size_t)4096 * 1024 * 2);
  float* kr_pre = (float*)alloc((size_t)4096 * 64 * 4);
  float* qr_pre = (float*)alloc((size_t)4096 * 1024 * 4);
  u16* kvbuf  = (u16*)alloc((size_t)4096 * 2048 * 2);
  u16* qbuf   = (u16*)alloc((size_t)4096 * 1024 * 2);
  // Qf..pad form a contiguous 64 MB region reused as f2 split-K partials
  u16* Qf     = (u16*)alloc((size_t)64 * 1024 * 128 * 2);   // 16 MB
  u16* Kf     = (u16*)alloc((size_t)64 * 1024 * 128 * 2);   // 16 MB
  u16* Vf     = (u16*)alloc((size_t)64 * 64 * 1024 * 2);    // 8 MB
  u16* attn_o = (u16*)alloc((size_t)4096 * 1024 * 2);       // 8 MB
  alloc((size_t)4096 * 1024 * 4);                           // 16 MB pad
  float* hbuf = (float*)alloc((size_t)4096 * 1024 * 4);
  u16* hn     = (u16*)alloc((size_t)4096 * 1024 * 2);
  u16* hid    = (u16*)alloc((size_t)4096 * 4096 * 2);
  float* partial = (float*)Qf;  // 4 x 16 MB, dead by f2 time

  TransArgs ta;
  const float* srcs[8] = {W_dkv, W_kr, W_qr, W_kv, W_q, W_o, W_f1, W_f2};
  u16* dsts[8] = {WT_dkv, WT_kr, WT_qr, WT_kv, WT_q, WT_o, WT_f1, WT_f2};
  const int Rs[8] = {1024, 1024, 1024, 512, 512, 1024, 1024, 4096};
  const int Cs[8] = {1024, 64, 1024, 2048, 1024, 1024, 4096, 1024};
  int acc_t = 0;
  for (int i = 0; i < 8; i++) {
    ta.src[i] = srcs[i]; ta.dst[i] = dsts[i]; ta.R[i] = Rs[i]; ta.C[i] = Cs[i];
    ta.base[i] = acc_t;
    acc_t += (Rs[i] >> 5) * (Cs[i] >> 5);
  }
  ta.base[8] = acc_t;
  ta.x = x; ta.rmsw = rms1; ta.xn = xn1;
  pre_all<<<acc_t + 4096, dim3(32, 8), 0, stream>>>(ta);

  gemmN<0, 2><<<dim3(32, 16), 256, 0, stream>>>(xn1, 1024, 0, WT_dkv, b_dkv, nullptr, comp, 1024, 1024);

  proj_fused<<<dim3(32, 33), 256, 0, stream>>>(comp,
      WT_qr, b_qr, qr_pre, WT_kr, b_kr, kr_pre,
      WT_kv, b_kv, kvbuf, WT_q, b_q, qbuf);

  rope_vtrans<<<4096 + 1024, 256, 0, stream>>>(qbuf, qr_pre, kvbuf, kr_pre, Qf, Kf, Vf);

  attn_mfma<<<B_ * NH_ * 8, 256, 0, stream>>>(Qf, Kf, Vf, attn_o);

  gemmN<3, 2><<<dim3(32, 16), 256, 0, stream>>>(attn_o, 1024, 0, WT_o, b_o, x, hbuf, 1024, 1024);

  rmsnorm_kernel<<<4096, 256, 0, stream>>>(hbuf, rms2, hn);

  gemmN<2, 4><<<dim3(32, 32), 256, 0, stream>>>(hn, 1024, 0, WT_f1, b_f1, nullptr, hid, 4096, 1024);

  gemm128_splitk<<<dim3(32, 8, 4), 256, 0, stream>>>(hid, 4096, WT_f2, partial, 1024, 4096, 1024);
  f2_reduce<<<4096, 256, 0, stream>>>(partial, hbuf, b_f2, out);
}

// Round 8
// 421.181 us; speedup vs baseline: 1.3863x; 1.0565x over previous
//
#include <hip/hip_runtime.h>

typedef unsigned int u32;
typedef unsigned short u16;
typedef __bf16 bf16x8 __attribute__((ext_vector_type(8)));
typedef float f32x4 __attribute__((ext_vector_type(4)));

#define B_ 4
#define T_ 1024
#define C_ 1024
#define NH_ 16
#define L_ 512
#define DHR_ 64
#define FF_ 4096

typedef __attribute__((address_space(3))) u32 as3_u32;
typedef __attribute__((address_space(1))) u32 as1_u32;

__device__ __forceinline__ void gld16(const u16* g, u16* l) {
  __builtin_amdgcn_global_load_lds((const as1_u32*)g, (as3_u32*)l, 16, 0, 0);
}

__device__ __forceinline__ float bf2f(u16 u) {
  union { u32 i; float f; } v; v.i = ((u32)u) << 16; return v.f;
}
__device__ __forceinline__ u16 f2bf(float f) {
  union { float f; u32 i; } v; v.f = f;
  u32 r = (v.i + 0x7FFFu + ((v.i >> 16) & 1u)) >> 16;
  return (u16)r;
}

// ---------------------------------------------------------------------------
// Fused pre-pass: 8 weight transposes (f32 [R,C] -> bf16 [C,R]) + rmsnorm1
// ---------------------------------------------------------------------------
struct TransArgs {
  const float* src[8];
  u16* dst[8];
  int R[8], C[8];
  int base[9];
  const float* x;
  const float* rmsw;
  u16* xn;
};

__global__ void pre_all(TransArgs ta) {
  const int bid = blockIdx.x;
  if (bid >= ta.base[8]) {  // rmsnorm row
    const int row = bid - ta.base[8];
    const int tid = threadIdx.y * 32 + threadIdx.x;
    const float* xp = ta.x + (size_t)row * C_;
    float v[4];
#pragma unroll
    for (int i = 0; i < 4; i++) v[i] = xp[tid + 256 * i];
    float ss = v[0] * v[0] + v[1] * v[1] + v[2] * v[2] + v[3] * v[3];
#pragma unroll
    for (int o = 32; o > 0; o >>= 1) ss += __shfl_down(ss, o, 64);
    __shared__ float red[4];
    if ((tid & 63) == 0) red[tid >> 6] = ss;
    __syncthreads();
    ss = red[0] + red[1] + red[2] + red[3];
    float scale = rsqrtf(ss * (1.0f / 1024.0f) + 1e-6f);
    u16* op = ta.xn + (size_t)row * C_;
#pragma unroll
    for (int i = 0; i < 4; i++)
      op[tid + 256 * i] = f2bf(v[i] * scale * ta.rmsw[tid + 256 * i]);
    return;
  }
  __shared__ float tile[32][33];
  int w = 0;
#pragma unroll
  for (int i = 1; i < 8; i++) w += (bid >= ta.base[i]);
  const int local = bid - ta.base[w];
  const int R = ta.R[w], C = ta.C[w];
  const int ctiles = C >> 5;
  const int bx = (local % ctiles) * 32;
  const int by = (local / ctiles) * 32;
  const float* in = ta.src[w];
  u16* outp = ta.dst[w];
  const int tx = threadIdx.x, ty = threadIdx.y;
  for (int i = ty; i < 32; i += 8)
    tile[i][tx] = in[(size_t)(by + i) * C + bx + tx];
  __syncthreads();
  for (int i = ty; i < 32; i += 8)
    outp[(size_t)(bx + i) * R + by + tx] = f2bf(tile[tx][i]);
}

// ---------------------------------------------------------------------------
// RMSNorm (standalone, for h)
// ---------------------------------------------------------------------------
__global__ __launch_bounds__(256) void rmsnorm_kernel(const float* __restrict__ xin,
                                                      const float* __restrict__ w,
                                                      u16* __restrict__ outp) {
  const int row = blockIdx.x;
  const int tid = threadIdx.x;
  const float* xp = xin + (size_t)row * C_;
  float v[4];
#pragma unroll
  for (int i = 0; i < 4; i++) v[i] = xp[tid + 256 * i];
  float ss = v[0] * v[0] + v[1] * v[1] + v[2] * v[2] + v[3] * v[3];
#pragma unroll
  for (int o = 32; o > 0; o >>= 1) ss += __shfl_down(ss, o, 64);
  __shared__ float red[4];
  if ((tid & 63) == 0) red[tid >> 6] = ss;
  __syncthreads();
  ss = red[0] + red[1] + red[2] + red[3];
  float scale = rsqrtf(ss * (1.0f / 1024.0f) + 1e-6f);
  u16* op = outp + (size_t)row * C_;
#pragma unroll
  for (int i = 0; i < 4; i++)
    op[tid + 256 * i] = f2bf(v[i] * scale * w[tid + 256 * i]);
}

// ---------------------------------------------------------------------------
// MFMA GEMM body, BK=64 with XOR-swizzled global_load_lds staging.
// LDS row stride = 64 elems (128 B). Thread (row=tid>>3, seg=tid&7) stages
// global segment seg^(row&7) at LDS position seg -> fragment ds_read_b128
// banks spread 2-way (free). Tile 128 x (NT*32). EPI: 0 bf16 | 1 f32 |
// 2 bf16+gelu | 3 f32+f32 resid | 4 f32 partial (no bias).
// ---------------------------------------------------------------------------
template<int EPI, bool NCLIP, int NT>
__device__ __forceinline__ void g_body(
    u16* As, u16* Bs,
    const u16* __restrict__ A, int lda, int aoff,
    const u16* __restrict__ BT, const float* __restrict__ bias,
    const float* __restrict__ resid, void* __restrict__ out,
    int N, int Kfull, int Klen, int m0, int n0, int koff) {
  const int tid = threadIdx.x;
  const int wave = tid >> 6, lane = tid & 63;
  const int wm = wave >> 1, wn = wave & 1;
  const int quad = lane >> 4, l15 = lane & 15;
  const int srow = tid >> 3;                    // 0..31
  const int gseg = (tid & 7) ^ (srow & 7);      // swizzled global segment

  const u16* aP = A + (size_t)(m0 + srow) * lda + aoff + koff + gseg * 8;
  const u16* bP = BT + (size_t)(n0 + srow) * Kfull + koff + gseg * 8;
  u16* aL = As + tid * 8;   // srow*64 + (tid&7)*8
  u16* bL = Bs + tid * 8;
  const size_t aStep = (size_t)32 * lda;
  const size_t bStep = (size_t)32 * Kfull;

  f32x4 acc[4][NT] = {};

  for (int k0 = 0; k0 < Klen; k0 += 64) {
#pragma unroll
    for (int c = 0; c < 4; c++)
      gld16(aP + k0 + c * aStep, aL + c * 32 * 64);
#pragma unroll
    for (int c = 0; c < NT; c++)
      gld16(bP + k0 + c * bStep, bL + c * 32 * 64);
    __syncthreads();
#pragma unroll
    for (int kh = 0; kh < 2; kh++) {
      bf16x8 af[4], bfr[NT];
#pragma unroll
      for (int mt = 0; mt < 4; mt++) {
        const int r = wm * 64 + mt * 16 + l15;
        const int p = (kh * 4 + quad) ^ (r & 7);
        af[mt] = *(const bf16x8*)&As[r * 64 + p * 8];
      }
#pragma unroll
      for (int nt = 0; nt < NT; nt++) {
        const int r = wn * (NT * 16) + nt * 16 + l15;
        const int p = (kh * 4 + quad) ^ (r & 7);
        bfr[nt] = *(const bf16x8*)&Bs[r * 64 + p * 8];
      }
#pragma unroll
      for (int mt = 0; mt < 4; mt++)
#pragma unroll
        for (int nt = 0; nt < NT; nt++)
          acc[mt][nt] = __builtin_amdgcn_mfma_f32_16x16x32_bf16(af[mt], bfr[nt], acc[mt][nt], 0, 0, 0);
    }
    __syncthreads();
  }

  float bvv[NT];
#pragma unroll
  for (int nt = 0; nt < NT; nt++) {
    const int gn = n0 + wn * (NT * 16) + nt * 16 + l15;
    bvv[nt] = (EPI == 4) ? 0.0f : ((NCLIP && gn >= N) ? 0.0f : bias[gn]);
  }
#pragma unroll
  for (int mt = 0; mt < 4; mt++) {
#pragma unroll
    for (int i = 0; i < 4; i++) {
      const int gm = m0 + wm * 64 + mt * 16 + quad * 4 + i;
      const size_t rowb = (size_t)gm * N;
#pragma unroll
      for (int nt = 0; nt < NT; nt++) {
        const int gn = n0 + wn * (NT * 16) + nt * 16 + l15;
        if (NCLIP && gn >= N) continue;
        const size_t oidx = rowb + gn;
        float v = acc[mt][nt][i] + bvv[nt];
        if (EPI == 2) {  // fast tanh-gelu: x*t/(t+1), t=e^{2y}
          float y = 0.7978845608028654f * (v + 0.044715f * v * v * v);
          float t = __expf(fminf(2.0f * y, 80.0f));
          v = v * t / (t + 1.0f);
        }
        if (EPI == 3) v += resid[oidx];
        if (EPI == 1 || EPI == 3 || EPI == 4) ((float*)out)[oidx] = v;
        else ((u16*)out)[oidx] = f2bf(v);
      }
    }
  }
}

template<int EPI, int NT>
__global__ __launch_bounds__(256) void gemmN(
    const u16* __restrict__ A, int lda, int aoff,
    const u16* __restrict__ BT, const float* __restrict__ bias,
    const float* __restrict__ resid, void* __restrict__ out,
    int N, int K) {
  __shared__ __align__(16) u16 As[128 * 64];
  __shared__ __align__(16) u16 Bs[NT * 32 * 64];
  g_body<EPI, false, NT>(As, Bs, A, lda, aoff, BT, bias, resid, out,
                         N, K, K, blockIdx.x * 128, blockIdx.y * (NT * 32), 0);
}

// split-K (blockIdx.z = K chunk) -> f32 partials, no bias
__global__ __launch_bounds__(256) void gemm128_splitk(
    const u16* __restrict__ A, int lda, const u16* __restrict__ BT,
    float* __restrict__ part, int N, int Kfull, int Klen) {
  __shared__ __align__(16) u16 As[128 * 64];
  __shared__ __align__(16) u16 Bs[128 * 64];
  const int z = blockIdx.z;
  g_body<4, false, 4>(As, Bs, A, lda, 0, BT, nullptr, nullptr,
                      part + (size_t)z * 4096 * N,
                      N, Kfull, Klen, blockIdx.x * 128, blockIdx.y * 128, z * Klen);
}

// out = h + bias + part[0..1]   (split-K=2)
__global__ __launch_bounds__(256) void f2_reduce(
    const float* __restrict__ part, const float* __restrict__ h,
    const float* __restrict__ bias, float* __restrict__ out) {
  const size_t base = (size_t)blockIdx.x * 1024;
  const size_t PS = (size_t)4096 * 1024;
#pragma unroll
  for (int i = 0; i < 4; i++) {
    const int col = threadIdx.x + 256 * i;
    out[base + col] = h[base + col] + bias[col] + part[base + col] +
                      part[PS + base + col];
  }
}

// ---------------------------------------------------------------------------
// Fused qr/kr/kv/q projections, all reading comp. grid (32, 33).
// ---------------------------------------------------------------------------
__global__ __launch_bounds__(256) void proj_fused(
    const u16* __restrict__ comp,
    const u16* __restrict__ WT_qr, const float* __restrict__ b_qr, float* __restrict__ qr_pre,
    const u16* __restrict__ WT_kr, const float* __restrict__ b_kr, float* __restrict__ kr_pre,
    const u16* __restrict__ WT_kv, const float* __restrict__ b_kv, u16* __restrict__ kvbuf,
    const u16* __restrict__ WT_q, const float* __restrict__ b_q, u16* __restrict__ qbuf) {
  __shared__ __align__(16) u16 As[128 * 64];
  __shared__ __align__(16) u16 Bs[128 * 64];
  const int m0 = blockIdx.x * 128;
  const int ny = blockIdx.y;
  if (ny < 8)
    g_body<1, false, 4>(As, Bs, comp, 1024, 0, WT_qr, b_qr, nullptr, qr_pre, 1024, 1024, 1024, m0, ny * 128, 0);
  else if (ny == 8)
    g_body<1, true, 4>(As, Bs, comp, 1024, 0, WT_kr, b_kr, nullptr, kr_pre, 64, 1024, 1024, m0, 0, 0);
  else if (ny < 25)
    g_body<0, false, 4>(As, Bs, comp, 1024, 0, WT_kv, b_kv, nullptr, kvbuf, 2048, 512, 512, m0, (ny - 9) * 128, 0);
  else
    g_body<0, false, 4>(As, Bs, comp, 1024, 512, WT_q, b_q, nullptr, qbuf, 1024, 512, 512, m0, (ny - 25) * 128, 0);
}

// ---------------------------------------------------------------------------
// Fused RoPE head-assembly (blocks 0..4095) + V transpose (blocks 4096..5119)
// ---------------------------------------------------------------------------
__global__ __launch_bounds__(256) void rope_vtrans(
    const u16* __restrict__ qb, const float* __restrict__ qr_pre,
    const u16* __restrict__ kvb, const float* __restrict__ kr_pre,
    u16* __restrict__ Qf, u16* __restrict__ Kf, u16* __restrict__ Vf) {
  __shared__ u16 tile[64][72];
  if (blockIdx.x >= 4096) {  // vtrans
    const int bid2 = blockIdx.x - 4096;
    const int bh = bid2 & 63, t0 = (bid2 >> 6) * 64;
    const int b = bh >> 4, h = bh & 15;
    const int r = threadIdx.x >> 2, seg = (threadIdx.x & 3) * 16;
    const u16* src = &kvb[((size_t)(b * 1024) + t0 + r) * 2048 + 1024 + h * 64 + seg];
    *(uint4*)&tile[r][seg] = *(const uint4*)src;
    *(uint4*)&tile[r][seg + 8] = *(const uint4*)(src + 8);
    __syncthreads();
    const int d = threadIdx.x >> 2, ts = (threadIdx.x & 3) * 16;
    u16 tmp[16];
#pragma unroll
    for (int j = 0; j < 16; j++) tmp[j] = tile[ts + j][d];
    u16* dst = &Vf[((size_t)bh * 64 + d) * 1024 + t0 + ts];
    *(uint4*)dst = *(uint4*)tmp;
    *(uint4*)(dst + 8) = *(uint4*)(tmp + 8);
    return;
  }
  const int bt = blockIdx.x;
  const int b = bt >> 10, t = bt & 1023;
  const float freq = (float)(t + 1);
  for (int idx = threadIdx.x; idx < 2048; idx += 256) {
    const int h = idx >> 7, d = idx & 127;
    const size_t dst = (((size_t)(b * 16 + h)) * T_ + t) * 128 + d;
    u16 qv, kvv;
    if (d < 64) {
      qv = qb[(size_t)bt * C_ + h * 64 + d];
      kvv = kvb[(size_t)bt * 2048 + h * 64 + d];
    } else {
      const int dd = d - 64;
      {
        const int g = h * 64 + dd;
        const int p = g >> 1;
        const float theta = __expf(-(float)(2 * p) * (9.210340372f / 1024.0f));
        float s, c;
        sincosf(freq * theta, &s, &c);
        const float x0 = qr_pre[(size_t)bt * 1024 + (p << 1)];
        const float x1 = qr_pre[(size_t)bt * 1024 + (p << 1) + 1];
        qv = f2bf((g & 1) ? (x1 * c + x0 * s) : (x0 * c - x1 * s));
      }
      {
        const int p = dd >> 1;
        const float theta = __expf(-(float)(2 * p) * (9.210340372f / 64.0f));
        float s, c;
        sincosf(freq * theta, &s, &c);
        const float x0 = kr_pre[(size_t)bt * 64 + (p << 1)];
        const float x1 = kr_pre[(size_t)bt * 64 + (p << 1) + 1];
        kvv = f2bf((dd & 1) ? (x1 * c + x0 * s) : (x0 * c - x1 * s));
      }
    }
    Qf[dst] = qv;
    Kf[dst] = kvv;
  }
}

// ---------------------------------------------------------------------------
// MFMA flash attention (balanced pairing, unchanged)
// ---------------------------------------------------------------------------
#define KSTR 136
#define VSTR 72

__device__ __forceinline__ void attn_tile(
    u16* Ks, u16* Vt, u16* Ps,
    const u16* __restrict__ Qf, const u16* __restrict__ Kf,
    const u16* __restrict__ Vf, u16* __restrict__ attn_o,
    int b, int h, int qt) {
  const int tid = threadIdx.x;
  const int wave = tid >> 6, lane = tid & 63;
  const int quad = lane >> 4, l15 = lane & 15;
  const int q0 = qt * 64;
  const size_t bh = (size_t)(b * 16 + h);

  bf16x8 qfrag[4];
  {
    const u16* qb = &Qf[(bh * T_ + q0 + wave * 16 + l15) * 128 + quad * 8];
#pragma unroll
    for (int kc = 0; kc < 4; kc++) qfrag[kc] = *(const bf16x8*)(qb + kc * 32);
  }

  f32x4 acc_o[4] = {};
  float m_i[4], l_i[4];
#pragma unroll
  for (int i = 0; i < 4; i++) { m_i[i] = -3.0e38f; l_i[i] = 0.0f; }

  const int kr_ = tid >> 3, kcs = (tid & 7) * 16;
  const int vd = tid >> 2, vts = (tid & 3) * 16;
  u16* Pw = Ps + wave * 16 * VSTR;

  for (int kt = 0; kt <= qt; kt++) {
    __syncthreads();
    {
      const u16* s0 = &Kf[(bh * T_ + kt * 64 + kr_) * 128 + kcs];
      const u16* s1 = s0 + 32 * 128;
      *(uint4*)&Ks[kr_ * KSTR + kcs] = *(const uint4*)s0;
      *(uint4*)&Ks[kr_ * KSTR + kcs + 8] = *(const uint4*)(s0 + 8);
      *(uint4*)&Ks[(kr_ + 32) * KSTR + kcs] = *(const uint4*)s1;
      *(uint4*)&Ks[(kr_ + 32) * KSTR + kcs + 8] = *(const uint4*)(s1 + 8);
      const u16* vs = &Vf[(bh * 64 + vd) * 1024 + kt * 64 + vts];
      *(uint4*)&Vt[vd * VSTR + vts] = *(const uint4*)vs;
      *(uint4*)&Vt[vd * VSTR + vts + 8] = *(const uint4*)(vs + 8);
    }
    __syncthreads();

    f32x4 acc_s[4] = {};
#pragma unroll
    for (int kc = 0; kc < 4; kc++) {
#pragma unroll
      for (int ng = 0; ng < 4; ng++) {
        bf16x8 bb = *(const bf16x8*)&Ks[(ng * 16 + l15) * KSTR + kc * 32 + quad * 8];
        acc_s[ng] = __builtin_amdgcn_mfma_f32_16x16x32_bf16(qfrag[kc], bb, acc_s[ng], 0, 0, 0);
      }
    }

    float sv[4][4];
#pragma unroll
    for (int ng = 0; ng < 4; ng++)
#pragma unroll
      for (int i = 0; i < 4; i++) {
        float s = acc_s[ng][i] * 0.125f;
        if (kt == qt && (ng * 16 + l15) > (wave * 16 + quad * 4 + i)) s = -3.0e38f;
        sv[ng][i] = s;
      }

    float alpha[4], mx[4];
#pragma unroll
    for (int i = 0; i < 4; i++) {
      float m = fmaxf(fmaxf(sv[0][i], sv[1][i]), fmaxf(sv[2][i], sv[3][i]));
#pragma unroll
      for (int off = 1; off < 16; off <<= 1) m = fmaxf(m, __shfl_xor(m, off, 64));
      float mn = fmaxf(m_i[i], m);
      alpha[i] = __expf(m_i[i] - mn);
      m_i[i] = mn;
      mx[i] = mn;
    }
    float rs[4] = {0.f, 0.f, 0.f, 0.f};
#pragma unroll
    for (int ng = 0; ng < 4; ng++)
#pragma unroll
      for (int i = 0; i < 4; i++) {
        float p = __expf(sv[ng][i] - mx[i]);
        rs[i] += p;
        Pw[(quad * 4 + i) * VSTR + ng * 16 + l15] = f2bf(p);
      }
#pragma unroll
    for (int i = 0; i < 4; i++) {
      float r = rs[i];
#pragma unroll
      for (int off = 1; off < 16; off <<= 1) r += __shfl_xor(r, off, 64);
      l_i[i] = l_i[i] * alpha[i] + r;
    }

#pragma unroll
    for (int ng = 0; ng < 4; ng++)
#pragma unroll
      for (int i = 0; i < 4; i++) acc_o[ng][i] *= alpha[i];
#pragma unroll
    for (int kc = 0; kc < 2; kc++) {
      bf16x8 a = *(const bf16x8*)&Pw[l15 * VSTR + kc * 32 + quad * 8];
#pragma unroll
      for (int ng = 0; ng < 4; ng++) {
        bf16x8 bb = *(const bf16x8*)&Vt[(ng * 16 + l15) * VSTR + kc * 32 + quad * 8];
        acc_o[ng] = __builtin_amdgcn_mfma_f32_16x16x32_bf16(a, bb, acc_o[ng], 0, 0, 0);
      }
    }
  }

  float linv[4];
#pragma unroll
  for (int i = 0; i < 4; i++) linv[i] = 1.0f / l_i[i];
#pragma unroll
  for (int ng = 0; ng < 4; ng++)
#pragma unroll
    for (int i = 0; i < 4; i++) {
      const int qrow = q0 + wave * 16 + quad * 4 + i;
      attn_o[((size_t)(b * T_) + qrow) * C_ + h * 64 + ng * 16 + l15] =
          f2bf(acc_o[ng][i] * linv[i]);
    }
}

__global__ __launch_bounds__(256) void attn_mfma(
    const u16* __restrict__ Qf, const u16* __restrict__ Kf,
    const u16* __restrict__ Vf, u16* __restrict__ attn_o) {
  __shared__ __align__(16) u16 Ks[64 * KSTR];
  __shared__ __align__(16) u16 Vt[64 * VSTR];
  __shared__ __align__(16) u16 Ps[4 * 16 * VSTR];
  const int j = blockIdx.x & 7;
  const int h = (blockIdx.x >> 3) & 15;
  const int b = blockIdx.x >> 7;
  attn_tile(Ks, Vt, Ps, Qf, Kf, Vf, attn_o, b, h, 15 - j);
  attn_tile(Ks, Vt, Ps, Qf, Kf, Vf, attn_o, b, h, j);
}

// ---------------------------------------------------------------------------
extern "C" void kernel_launch(void* const* d_in, const int* in_sizes, int n_in,
                              void* d_out, int out_size, void* d_ws, size_t ws_size,
                              hipStream_t stream) {
  const float* x = (const float*)d_in[0];
  const float* rms1 = (const float*)d_in[1];
  const float* rms2 = (const float*)d_in[2];
  const float* W_dkv = (const float*)d_in[3];
  const float* b_dkv = (const float*)d_in[4];
  const float* W_kr = (const float*)d_in[5];
  const float* b_kr = (const float*)d_in[6];
  const float* W_qr = (const float*)d_in[7];
  const float* b_qr = (const float*)d_in[8];
  const float* W_kv = (const float*)d_in[9];
  const float* b_kv = (const float*)d_in[10];
  const float* W_q = (const float*)d_in[11];
  const float* b_q = (const float*)d_in[12];
  const float* W_o = (const float*)d_in[13];
  const float* b_o = (const float*)d_in[14];
  const float* W_f1 = (const float*)d_in[15];
  const float* b_f1 = (const float*)d_in[16];
  const float* W_f2 = (const float*)d_in[17];
  const float* b_f2 = (const float*)d_in[18];
  float* out = (float*)d_out;

  char* ws = (char*)d_ws;
  size_t off = 0;
  auto alloc = [&](size_t bytes) -> void* {
    void* p = ws + off;
    off += (bytes + 255) & ~(size_t)255;
    return p;
  };
  u16* WT_dkv = (u16*)alloc((size_t)1024 * 1024 * 2);
  u16* WT_kr  = (u16*)alloc((size_t)128 * 1024 * 2);
  u16* WT_qr  = (u16*)alloc((size_t)1024 * 1024 * 2);
  u16* WT_kv  = (u16*)alloc((size_t)2048 * 512 * 2);
  u16* WT_q   = (u16*)alloc((size_t)1024 * 512 * 2);
  u16* WT_o   = (u16*)alloc((size_t)1024 * 1024 * 2);
  u16* WT_f1  = (u16*)alloc((size_t)4096 * 1024 * 2);
  u16* WT_f2  = (u16*)alloc((size_t)1024 * 4096 * 2);
  u16* xn1    = (u16*)alloc((size_t)4096 * 1024 * 2);
  u16* comp   = (u16*)alloc((size_t)4096 * 1024 * 2);
  float* kr_pre = (float*)alloc((size_t)4096 * 64 * 4);
  float* qr_pre = (float*)alloc((size_t)4096 * 1024 * 4);
  u16* kvbuf  = (u16*)alloc((size_t)4096 * 2048 * 2);
  u16* qbuf   = (u16*)alloc((size_t)4096 * 1024 * 2);
  // Qf+Kf form a contiguous 32 MB region reused as f2 split-K partials
  u16* Qf     = (u16*)alloc((size_t)64 * 1024 * 128 * 2);   // 16 MB
  u16* Kf     = (u16*)alloc((size_t)64 * 1024 * 128 * 2);   // 16 MB
  u16* Vf     = (u16*)alloc((size_t)64 * 64 * 1024 * 2);    // 8 MB
  u16* attn_o = (u16*)alloc((size_t)4096 * 1024 * 2);       // 8 MB
  float* hbuf = (float*)alloc((size_t)4096 * 1024 * 4);
  u16* hn     = (u16*)alloc((size_t)4096 * 1024 * 2);
  u16* hid    = (u16*)alloc((size_t)4096 * 4096 * 2);
  float* partial = (float*)Qf;  // 2 x 16 MB, dead by f2 time

  TransArgs ta;
  const float* srcs[8] = {W_dkv, W_kr, W_qr, W_kv, W_q, W_o, W_f1, W_f2};
  u16* dsts[8] = {WT_dkv, WT_kr, WT_qr, WT_kv, WT_q, WT_o, WT_f1, WT_f2};
  const int Rs[8] = {1024, 1024, 1024, 512, 512, 1024, 1024, 4096};
  const int Cs[8] = {1024, 64, 1024, 2048, 1024, 1024, 4096, 1024};
  int acc_t = 0;
  for (int i = 0; i < 8; i++) {
    ta.src[i] = srcs[i]; ta.dst[i] = dsts[i]; ta.R[i] = Rs[i]; ta.C[i] = Cs[i];
    ta.base[i] = acc_t;
    acc_t += (Rs[i] >> 5) * (Cs[i] >> 5);
  }
  ta.base[8] = acc_t;
  ta.x = x; ta.rmsw = rms1; ta.xn = xn1;
  pre_all<<<acc_t + 4096, dim3(32, 8), 0, stream>>>(ta);

  gemmN<0, 2><<<dim3(32, 16), 256, 0, stream>>>(xn1, 1024, 0, WT_dkv, b_dkv, nullptr, comp, 1024, 1024);

  proj_fused<<<dim3(32, 33), 256, 0, stream>>>(comp,
      WT_qr, b_qr, qr_pre, WT_kr, b_kr, kr_pre,
      WT_kv, b_kv, kvbuf, WT_q, b_q, qbuf);

  rope_vtrans<<<4096 + 1024, 256, 0, stream>>>(qbuf, qr_pre, kvbuf, kr_pre, Qf, Kf, Vf);

  attn_mfma<<<B_ * NH_ * 8, 256, 0, stream>>>(Qf, Kf, Vf, attn_o);

  gemmN<3, 2><<<dim3(32, 16), 256, 0, stream>>>(attn_o, 1024, 0, WT_o, b_o, x, hbuf, 1024, 1024);

  rmsnorm_kernel<<<4096, 256, 0, stream>>>(hbuf, rms2, hn);

  gemmN<2, 4><<<dim3(32, 32), 256, 0, stream>>>(hn, 1024, 0, WT_f1, b_f1, nullptr, hid, 4096, 1024);

  gemm128_splitk<<<dim3(32, 8, 2), 256, 0, stream>>>(hid, 4096, WT_f2, partial, 1024, 4096, 2048);
  f2_reduce<<<4096, 256, 0, stream>>>(partial, hbuf, b_f2, out);
}

// Round 9
// 416.536 us; speedup vs baseline: 1.4018x; 1.0112x over previous
//
#include <hip/hip_runtime.h>

typedef unsigned int u32;
typedef unsigned short u16;
typedef __bf16 bf16x8 __attribute__((ext_vector_type(8)));
typedef float f32x4 __attribute__((ext_vector_type(4)));

#define B_ 4
#define T_ 1024
#define C_ 1024
#define NH_ 16
#define L_ 512
#define DHR_ 64
#define FF_ 4096

typedef __attribute__((address_space(3))) u32 as3_u32;
typedef __attribute__((address_space(1))) u32 as1_u32;

__device__ __forceinline__ void gld16(const u16* g, u16* l) {
  __builtin_amdgcn_global_load_lds((const as1_u32*)g, (as3_u32*)l, 16, 0, 0);
}

__device__ __forceinline__ float bf2f(u16 u) {
  union { u32 i; float f; } v; v.i = ((u32)u) << 16; return v.f;
}
__device__ __forceinline__ u16 f2bf(float f) {
  union { float f; u32 i; } v; v.f = f;
  u32 r = (v.i + 0x7FFFu + ((v.i >> 16) & 1u)) >> 16;
  return (u16)r;
}

// ---------------------------------------------------------------------------
// Fused pre-pass: 8 weight transposes (f32 [R,C] -> bf16 [C,R]) + rmsnorm1
// ---------------------------------------------------------------------------
struct TransArgs {
  const float* src[8];
  u16* dst[8];
  int R[8], C[8];
  int base[9];
  const float* x;
  const float* rmsw;
  u16* xn;
};

__global__ void pre_all(TransArgs ta) {
  const int bid = blockIdx.x;
  if (bid >= ta.base[8]) {  // rmsnorm row
    const int row = bid - ta.base[8];
    const int tid = threadIdx.y * 32 + threadIdx.x;
    const float* xp = ta.x + (size_t)row * C_;
    float v[4];
#pragma unroll
    for (int i = 0; i < 4; i++) v[i] = xp[tid + 256 * i];
    float ss = v[0] * v[0] + v[1] * v[1] + v[2] * v[2] + v[3] * v[3];
#pragma unroll
    for (int o = 32; o > 0; o >>= 1) ss += __shfl_down(ss, o, 64);
    __shared__ float red[4];
    if ((tid & 63) == 0) red[tid >> 6] = ss;
    __syncthreads();
    ss = red[0] + red[1] + red[2] + red[3];
    float scale = rsqrtf(ss * (1.0f / 1024.0f) + 1e-6f);
    u16* op = ta.xn + (size_t)row * C_;
#pragma unroll
    for (int i = 0; i < 4; i++)
      op[tid + 256 * i] = f2bf(v[i] * scale * ta.rmsw[tid + 256 * i]);
    return;
  }
  __shared__ float tile[32][33];
  int w = 0;
#pragma unroll
  for (int i = 1; i < 8; i++) w += (bid >= ta.base[i]);
  const int local = bid - ta.base[w];
  const int R = ta.R[w], C = ta.C[w];
  const int ctiles = C >> 5;
  const int bx = (local % ctiles) * 32;
  const int by = (local / ctiles) * 32;
  const float* in = ta.src[w];
  u16* outp = ta.dst[w];
  const int tx = threadIdx.x, ty = threadIdx.y;
  for (int i = ty; i < 32; i += 8)
    tile[i][tx] = in[(size_t)(by + i) * C + bx + tx];
  __syncthreads();
  for (int i = ty; i < 32; i += 8)
    outp[(size_t)(bx + i) * R + by + tx] = f2bf(tile[tx][i]);
}

// ---------------------------------------------------------------------------
// RMSNorm (standalone, for h)
// ---------------------------------------------------------------------------
__global__ __launch_bounds__(256) void rmsnorm_kernel(const float* __restrict__ xin,
                                                      const float* __restrict__ w,
                                                      u16* __restrict__ outp) {
  const int row = blockIdx.x;
  const int tid = threadIdx.x;
  const float* xp = xin + (size_t)row * C_;
  float v[4];
#pragma unroll
  for (int i = 0; i < 4; i++) v[i] = xp[tid + 256 * i];
  float ss = v[0] * v[0] + v[1] * v[1] + v[2] * v[2] + v[3] * v[3];
#pragma unroll
  for (int o = 32; o > 0; o >>= 1) ss += __shfl_down(ss, o, 64);
  __shared__ float red[4];
  if ((tid & 63) == 0) red[tid >> 6] = ss;
  __syncthreads();
  ss = red[0] + red[1] + red[2] + red[3];
  float scale = rsqrtf(ss * (1.0f / 1024.0f) + 1e-6f);
  u16* op = outp + (size_t)row * C_;
#pragma unroll
  for (int i = 0; i < 4; i++)
    op[tid + 256 * i] = f2bf(v[i] * scale * w[tid + 256 * i]);
}

// ---------------------------------------------------------------------------
// MFMA GEMM body, BK=64 with XOR-swizzled global_load_lds staging.
// ---------------------------------------------------------------------------
template<int EPI, bool NCLIP, int NT>
__device__ __forceinline__ void g_body(
    u16* As, u16* Bs,
    const u16* __restrict__ A, int lda, int aoff,
    const u16* __restrict__ BT, const float* __restrict__ bias,
    const float* __restrict__ resid, void* __restrict__ out,
    int N, int Kfull, int Klen, int m0, int n0, int koff) {
  const int tid = threadIdx.x;
  const int wave = tid >> 6, lane = tid & 63;
  const int wm = wave >> 1, wn = wave & 1;
  const int quad = lane >> 4, l15 = lane & 15;
  const int srow = tid >> 3;
  const int gseg = (tid & 7) ^ (srow & 7);

  const u16* aP = A + (size_t)(m0 + srow) * lda + aoff + koff + gseg * 8;
  const u16* bP = BT + (size_t)(n0 + srow) * Kfull + koff + gseg * 8;
  u16* aL = As + tid * 8;
  u16* bL = Bs + tid * 8;
  const size_t aStep = (size_t)32 * lda;
  const size_t bStep = (size_t)32 * Kfull;

  f32x4 acc[4][NT] = {};

  for (int k0 = 0; k0 < Klen; k0 += 64) {
#pragma unroll
    for (int c = 0; c < 4; c++)
      gld16(aP + k0 + c * aStep, aL + c * 32 * 64);
#pragma unroll
    for (int c = 0; c < NT; c++)
      gld16(bP + k0 + c * bStep, bL + c * 32 * 64);
    __syncthreads();
#pragma unroll
    for (int kh = 0; kh < 2; kh++) {
      bf16x8 af[4], bfr[NT];
#pragma unroll
      for (int mt = 0; mt < 4; mt++) {
        const int r = wm * 64 + mt * 16 + l15;
        const int p = (kh * 4 + quad) ^ (r & 7);
        af[mt] = *(const bf16x8*)&As[r * 64 + p * 8];
      }
#pragma unroll
      for (int nt = 0; nt < NT; nt++) {
        const int r = wn * (NT * 16) + nt * 16 + l15;
        const int p = (kh * 4 + quad) ^ (r & 7);
        bfr[nt] = *(const bf16x8*)&Bs[r * 64 + p * 8];
      }
#pragma unroll
      for (int mt = 0; mt < 4; mt++)
#pragma unroll
        for (int nt = 0; nt < NT; nt++)
          acc[mt][nt] = __builtin_amdgcn_mfma_f32_16x16x32_bf16(af[mt], bfr[nt], acc[mt][nt], 0, 0, 0);
    }
    __syncthreads();
  }

  float bvv[NT];
#pragma unroll
  for (int nt = 0; nt < NT; nt++) {
    const int gn = n0 + wn * (NT * 16) + nt * 16 + l15;
    bvv[nt] = (EPI == 4) ? 0.0f : ((NCLIP && gn >= N) ? 0.0f : bias[gn]);
  }
#pragma unroll
  for (int mt = 0; mt < 4; mt++) {
#pragma unroll
    for (int i = 0; i < 4; i++) {
      const int gm = m0 + wm * 64 + mt * 16 + quad * 4 + i;
      const size_t rowb = (size_t)gm * N;
#pragma unroll
      for (int nt = 0; nt < NT; nt++) {
        const int gn = n0 + wn * (NT * 16) + nt * 16 + l15;
        if (NCLIP && gn >= N) continue;
        const size_t oidx = rowb + gn;
        float v = acc[mt][nt][i] + bvv[nt];
        if (EPI == 2) {  // fast tanh-gelu: x*t/(t+1), t=e^{2y}
          float y = 0.7978845608028654f * (v + 0.044715f * v * v * v);
          float t = __expf(fminf(2.0f * y, 80.0f));
          v = v * t / (t + 1.0f);
        }
        if (EPI == 3) v += resid[oidx];
        if (EPI == 1 || EPI == 3 || EPI == 4) ((float*)out)[oidx] = v;
        else ((u16*)out)[oidx] = f2bf(v);
      }
    }
  }
}

template<int EPI, int NT>
__global__ __launch_bounds__(256) void gemmN(
    const u16* __restrict__ A, int lda, int aoff,
    const u16* __restrict__ BT, const float* __restrict__ bias,
    const float* __restrict__ resid, void* __restrict__ out,
    int N, int K) {
  __shared__ __align__(16) u16 As[128 * 64];
  __shared__ __align__(16) u16 Bs[NT * 32 * 64];
  g_body<EPI, false, NT>(As, Bs, A, lda, aoff, BT, bias, resid, out,
                         N, K, K, blockIdx.x * 128, blockIdx.y * (NT * 32), 0);
}

// split-K (blockIdx.z = K chunk) -> f32 partials, no bias
__global__ __launch_bounds__(256) void gemm128_splitk(
    const u16* __restrict__ A, int lda, const u16* __restrict__ BT,
    float* __restrict__ part, int N, int Kfull, int Klen) {
  __shared__ __align__(16) u16 As[128 * 64];
  __shared__ __align__(16) u16 Bs[128 * 64];
  const int z = blockIdx.z;
  g_body<4, false, 4>(As, Bs, A, lda, 0, BT, nullptr, nullptr,
                      part + (size_t)z * 4096 * N,
                      N, Kfull, Klen, blockIdx.x * 128, blockIdx.y * 128, z * Klen);
}

// out = h + bias + part[0..1]   (split-K=2)
__global__ __launch_bounds__(256) void f2_reduce(
    const float* __restrict__ part, const float* __restrict__ h,
    const float* __restrict__ bias, float* __restrict__ out) {
  const size_t base = (size_t)blockIdx.x * 1024;
  const size_t PS = (size_t)4096 * 1024;
#pragma unroll
  for (int i = 0; i < 4; i++) {
    const int col = threadIdx.x + 256 * i;
    out[base + col] = h[base + col] + bias[col] + part[base + col] +
                      part[PS + base + col];
  }
}

// ---------------------------------------------------------------------------
// Fused qr/kr/kv/q projections, all reading comp. grid (32, 33).
// ---------------------------------------------------------------------------
__global__ __launch_bounds__(256) void proj_fused(
    const u16* __restrict__ comp,
    const u16* __restrict__ WT_qr, const float* __restrict__ b_qr, float* __restrict__ qr_pre,
    const u16* __restrict__ WT_kr, const float* __restrict__ b_kr, float* __restrict__ kr_pre,
    const u16* __restrict__ WT_kv, const float* __restrict__ b_kv, u16* __restrict__ kvbuf,
    const u16* __restrict__ WT_q, const float* __restrict__ b_q, u16* __restrict__ qbuf) {
  __shared__ __align__(16) u16 As[128 * 64];
  __shared__ __align__(16) u16 Bs[128 * 64];
  const int m0 = blockIdx.x * 128;
  const int ny = blockIdx.y;
  if (ny < 8)
    g_body<1, false, 4>(As, Bs, comp, 1024, 0, WT_qr, b_qr, nullptr, qr_pre, 1024, 1024, 1024, m0, ny * 128, 0);
  else if (ny == 8)
    g_body<1, true, 4>(As, Bs, comp, 1024, 0, WT_kr, b_kr, nullptr, kr_pre, 64, 1024, 1024, m0, 0, 0);
  else if (ny < 25)
    g_body<0, false, 4>(As, Bs, comp, 1024, 0, WT_kv, b_kv, nullptr, kvbuf, 2048, 512, 512, m0, (ny - 9) * 128, 0);
  else
    g_body<0, false, 4>(As, Bs, comp, 1024, 512, WT_q, b_q, nullptr, qbuf, 1024, 512, 512, m0, (ny - 25) * 128, 0);
}

// ---------------------------------------------------------------------------
// Fused RoPE head-assembly (blocks 0..4095) + V transpose (blocks 4096..5119)
// Builds Qf [B,NH,T,128], kRf [B,T,64] (head-independent RoPE'd kR), Vf.
// K is NOT materialized per-head: attention stages it from kvbuf + kRf.
// ---------------------------------------------------------------------------
__global__ __launch_bounds__(256) void rope_vtrans(
    const u16* __restrict__ qb, const float* __restrict__ qr_pre,
    const u16* __restrict__ kvb, const float* __restrict__ kr_pre,
    u16* __restrict__ Qf, u16* __restrict__ kRf, u16* __restrict__ Vf) {
  __shared__ u16 tile[64][72];
  if (blockIdx.x >= 4096) {  // vtrans
    const int bid2 = blockIdx.x - 4096;
    const int bh = bid2 & 63, t0 = (bid2 >> 6) * 64;
    const int b = bh >> 4, h = bh & 15;
    const int r = threadIdx.x >> 2, seg = (threadIdx.x & 3) * 16;
    const u16* src = &kvb[((size_t)(b * 1024) + t0 + r) * 2048 + 1024 + h * 64 + seg];
    *(uint4*)&tile[r][seg] = *(const uint4*)src;
    *(uint4*)&tile[r][seg + 8] = *(const uint4*)(src + 8);
    __syncthreads();
    const int d = threadIdx.x >> 2, ts = (threadIdx.x & 3) * 16;
    u16 tmp[16];
#pragma unroll
    for (int j = 0; j < 16; j++) tmp[j] = tile[ts + j][d];
    u16* dst = &Vf[((size_t)bh * 64 + d) * 1024 + t0 + ts];
    *(uint4*)dst = *(uint4*)tmp;
    *(uint4*)(dst + 8) = *(uint4*)(tmp + 8);
    return;
  }
  const int bt = blockIdx.x;
  const int b = bt >> 10, t = bt & 1023;
  const float freq = (float)(t + 1);
  for (int idx = threadIdx.x; idx < 2048; idx += 256) {
    const int h = idx >> 7, d = idx & 127;
    const size_t dst = (((size_t)(b * 16 + h)) * T_ + t) * 128 + d;
    if (d < 64) {
      Qf[dst] = qb[(size_t)bt * C_ + h * 64 + d];
    } else {
      const int dd = d - 64;
      const int g = h * 64 + dd;
      const int p = g >> 1;
      const float theta = __expf(-(float)(2 * p) * (9.210340372f / 1024.0f));
      float s, c;
      sincosf(freq * theta, &s, &c);
      const float x0 = qr_pre[(size_t)bt * 1024 + (p << 1)];
      const float x1 = qr_pre[(size_t)bt * 1024 + (p << 1) + 1];
      Qf[dst] = f2bf((g & 1) ? (x1 * c + x0 * s) : (x0 * c - x1 * s));
      if (h == 0) {  // kR is head-independent: write once
        const int p2 = dd >> 1;
        const float theta2 = __expf(-(float)(2 * p2) * (9.210340372f / 64.0f));
        float s2, c2;
        sincosf(freq * theta2, &s2, &c2);
        const float y0 = kr_pre[(size_t)bt * 64 + (p2 << 1)];
        const float y1 = kr_pre[(size_t)bt * 64 + (p2 << 1) + 1];
        kRf[(size_t)bt * 64 + dd] = f2bf((dd & 1) ? (y1 * c2 + y0 * s2) : (y0 * c2 - y1 * s2));
      }
    }
  }
}

// ---------------------------------------------------------------------------
// MFMA flash attention: K staged from kvbuf (head slice) + kRf (shared RoPE
// part). XCD-local block decode: bh in low 6 bits so all 8 j-blocks of one
// (b,h) share bid%8 -> same XCD L2 (K/V working set 3 MB < 4 MB).
// ---------------------------------------------------------------------------
#define KSTR 136
#define VSTR 72

__device__ __forceinline__ void attn_tile(
    u16* Ks, u16* Vt, u16* Ps,
    const u16* __restrict__ Qf, const u16* __restrict__ kvbuf,
    const u16* __restrict__ kRf, const u16* __restrict__ Vf,
    u16* __restrict__ attn_o, int b, int h, int qt) {
  const int tid = threadIdx.x;
  const int wave = tid >> 6, lane = tid & 63;
  const int quad = lane >> 4, l15 = lane & 15;
  const int q0 = qt * 64;
  const size_t bh = (size_t)(b * 16 + h);

  bf16x8 qfrag[4];
  {
    const u16* qb = &Qf[(bh * T_ + q0 + wave * 16 + l15) * 128 + quad * 8];
#pragma unroll
    for (int kc = 0; kc < 4; kc++) qfrag[kc] = *(const bf16x8*)(qb + kc * 32);
  }

  f32x4 acc_o[4] = {};
  float m_i[4], l_i[4];
#pragma unroll
  for (int i = 0; i < 4; i++) { m_i[i] = -3.0e38f; l_i[i] = 0.0f; }

  const int kr_ = tid >> 3, kcs = (tid & 7) * 16;
  const int vd = tid >> 2, vts = (tid & 3) * 16;
  u16* Pw = Ps + wave * 16 * VSTR;

  // K staging source: cols 0..63 from kvbuf k-half, 64..127 from kRf
  const bool isk = kcs < 64;
  const size_t rstep = isk ? (size_t)32 * 2048 : (size_t)32 * 64;

  for (int kt = 0; kt <= qt; kt++) {
    __syncthreads();
    {
      const int t_row = kt * 64 + kr_;
      const u16* s0 = isk
          ? &kvbuf[((size_t)(b * T_) + t_row) * 2048 + h * 64 + kcs]
          : &kRf[((size_t)(b * T_) + t_row) * 64 + (kcs - 64)];
      const u16* s1 = s0 + rstep;
      *(uint4*)&Ks[kr_ * KSTR + kcs] = *(const uint4*)s0;
      *(uint4*)&Ks[kr_ * KSTR + kcs + 8] = *(const uint4*)(s0 + 8);
      *(uint4*)&Ks[(kr_ + 32) * KSTR + kcs] = *(const uint4*)s1;
      *(uint4*)&Ks[(kr_ + 32) * KSTR + kcs + 8] = *(const uint4*)(s1 + 8);
      const u16* vs = &Vf[(bh * 64 + vd) * 1024 + kt * 64 + vts];
      *(uint4*)&Vt[vd * VSTR + vts] = *(const uint4*)vs;
      *(uint4*)&Vt[vd * VSTR + vts + 8] = *(const uint4*)(vs + 8);
    }
    __syncthreads();

    f32x4 acc_s[4] = {};
#pragma unroll
    for (int kc = 0; kc < 4; kc++) {
#pragma unroll
      for (int ng = 0; ng < 4; ng++) {
        bf16x8 bb = *(const bf16x8*)&Ks[(ng * 16 + l15) * KSTR + kc * 32 + quad * 8];
        acc_s[ng] = __builtin_amdgcn_mfma_f32_16x16x32_bf16(qfrag[kc], bb, acc_s[ng], 0, 0, 0);
      }
    }

    float sv[4][4];
#pragma unroll
    for (int ng = 0; ng < 4; ng++)
#pragma unroll
      for (int i = 0; i < 4; i++) {
        float s = acc_s[ng][i] * 0.125f;
        if (kt == qt && (ng * 16 + l15) > (wave * 16 + quad * 4 + i)) s = -3.0e38f;
        sv[ng][i] = s;
      }

    float alpha[4], mx[4];
#pragma unroll
    for (int i = 0; i < 4; i++) {
      float m = fmaxf(fmaxf(sv[0][i], sv[1][i]), fmaxf(sv[2][i], sv[3][i]));
#pragma unroll
      for (int off = 1; off < 16; off <<= 1) m = fmaxf(m, __shfl_xor(m, off, 64));
      float mn = fmaxf(m_i[i], m);
      alpha[i] = __expf(m_i[i] - mn);
      m_i[i] = mn;
      mx[i] = mn;
    }
    float rs[4] = {0.f, 0.f, 0.f, 0.f};
#pragma unroll
    for (int ng = 0; ng < 4; ng++)
#pragma unroll
      for (int i = 0; i < 4; i++) {
        float p = __expf(sv[ng][i] - mx[i]);
        rs[i] += p;
        Pw[(quad * 4 + i) * VSTR + ng * 16 + l15] = f2bf(p);
      }
#pragma unroll
    for (int i = 0; i < 4; i++) {
      float r = rs[i];
#pragma unroll
      for (int off = 1; off < 16; off <<= 1) r += __shfl_xor(r, off, 64);
      l_i[i] = l_i[i] * alpha[i] + r;
    }

#pragma unroll
    for (int ng = 0; ng < 4; ng++)
#pragma unroll
      for (int i = 0; i < 4; i++) acc_o[ng][i] *= alpha[i];
#pragma unroll
    for (int kc = 0; kc < 2; kc++) {
      bf16x8 a = *(const bf16x8*)&Pw[l15 * VSTR + kc * 32 + quad * 8];
#pragma unroll
      for (int ng = 0; ng < 4; ng++) {
        bf16x8 bb = *(const bf16x8*)&Vt[(ng * 16 + l15) * VSTR + kc * 32 + quad * 8];
        acc_o[ng] = __builtin_amdgcn_mfma_f32_16x16x32_bf16(a, bb, acc_o[ng], 0, 0, 0);
      }
    }
  }

  float linv[4];
#pragma unroll
  for (int i = 0; i < 4; i++) linv[i] = 1.0f / l_i[i];
#pragma unroll
  for (int ng = 0; ng < 4; ng++)
#pragma unroll
    for (int i = 0; i < 4; i++) {
      const int qrow = q0 + wave * 16 + quad * 4 + i;
      attn_o[((size_t)(b * T_) + qrow) * C_ + h * 64 + ng * 16 + l15] =
          f2bf(acc_o[ng][i] * linv[i]);
    }
}

__global__ __launch_bounds__(256) void attn_mfma(
    const u16* __restrict__ Qf, const u16* __restrict__ kvbuf,
    const u16* __restrict__ kRf, const u16* __restrict__ Vf,
    u16* __restrict__ attn_o) {
  __shared__ __align__(16) u16 Ks[64 * KSTR];
  __shared__ __align__(16) u16 Vt[64 * VSTR];
  __shared__ __align__(16) u16 Ps[4 * 16 * VSTR];
  // XCD-local decode: bh in LOW bits (bid%8 == bh%8 for all j)
  const int bh_lin = blockIdx.x & 63;
  const int j = blockIdx.x >> 6;
  const int h = bh_lin & 15;
  const int b = bh_lin >> 4;
  attn_tile(Ks, Vt, Ps, Qf, kvbuf, kRf, Vf, attn_o, b, h, 15 - j);
  attn_tile(Ks, Vt, Ps, Qf, kvbuf, kRf, Vf, attn_o, b, h, j);
}

// ---------------------------------------------------------------------------
extern "C" void kernel_launch(void* const* d_in, const int* in_sizes, int n_in,
                              void* d_out, int out_size, void* d_ws, size_t ws_size,
                              hipStream_t stream) {
  const float* x = (const float*)d_in[0];
  const float* rms1 = (const float*)d_in[1];
  const float* rms2 = (const float*)d_in[2];
  const float* W_dkv = (const float*)d_in[3];
  const float* b_dkv = (const float*)d_in[4];
  const float* W_kr = (const float*)d_in[5];
  const float* b_kr = (const float*)d_in[6];
  const float* W_qr = (const float*)d_in[7];
  const float* b_qr = (const float*)d_in[8];
  const float* W_kv = (const float*)d_in[9];
  const float* b_kv = (const float*)d_in[10];
  const float* W_q = (const float*)d_in[11];
  const float* b_q = (const float*)d_in[12];
  const float* W_o = (const float*)d_in[13];
  const float* b_o = (const float*)d_in[14];
  const float* W_f1 = (const float*)d_in[15];
  const float* b_f1 = (const float*)d_in[16];
  const float* W_f2 = (const float*)d_in[17];
  const float* b_f2 = (const float*)d_in[18];
  float* out = (float*)d_out;

  char* ws = (char*)d_ws;
  size_t off = 0;
  auto alloc = [&](size_t bytes) -> void* {
    void* p = ws + off;
    off += (bytes + 255) & ~(size_t)255;
    return p;
  };
  u16* WT_dkv = (u16*)alloc((size_t)1024 * 1024 * 2);
  u16* WT_kr  = (u16*)alloc((size_t)128 * 1024 * 2);
  u16* WT_qr  = (u16*)alloc((size_t)1024 * 1024 * 2);
  u16* WT_kv  = (u16*)alloc((size_t)2048 * 512 * 2);
  u16* WT_q   = (u16*)alloc((size_t)1024 * 512 * 2);
  u16* WT_o   = (u16*)alloc((size_t)1024 * 1024 * 2);
  u16* WT_f1  = (u16*)alloc((size_t)4096 * 1024 * 2);
  u16* WT_f2  = (u16*)alloc((size_t)1024 * 4096 * 2);
  u16* xn1    = (u16*)alloc((size_t)4096 * 1024 * 2);
  u16* comp   = (u16*)alloc((size_t)4096 * 1024 * 2);
  float* kr_pre = (float*)alloc((size_t)4096 * 64 * 4);
  float* qr_pre = (float*)alloc((size_t)4096 * 1024 * 4);
  u16* kvbuf  = (u16*)alloc((size_t)4096 * 2048 * 2);
  u16* qbuf   = (u16*)alloc((size_t)4096 * 1024 * 2);
  // Qf..attn_o form a contiguous ~32.5 MB region reused as f2 partials
  u16* Qf     = (u16*)alloc((size_t)64 * 1024 * 128 * 2);   // 16 MB
  u16* kRf    = (u16*)alloc((size_t)4096 * 64 * 2);         // 0.5 MB
  u16* Vf     = (u16*)alloc((size_t)64 * 64 * 1024 * 2);    // 8 MB
  u16* attn_o = (u16*)alloc((size_t)4096 * 1024 * 2);       // 8 MB
  float* hbuf = (float*)alloc((size_t)4096 * 1024 * 4);
  u16* hn     = (u16*)alloc((size_t)4096 * 1024 * 2);
  u16* hid    = (u16*)alloc((size_t)4096 * 4096 * 2);
  float* partial = (float*)Qf;  // 2 x 16 MB over Qf..attn_o, dead by f2 time

  TransArgs ta;
  const float* srcs[8] = {W_dkv, W_kr, W_qr, W_kv, W_q, W_o, W_f1, W_f2};
  u16* dsts[8] = {WT_dkv, WT_kr, WT_qr, WT_kv, WT_q, WT_o, WT_f1, WT_f2};
  const int Rs[8] = {1024, 1024, 1024, 512, 512, 1024, 1024, 4096};
  const int Cs[8] = {1024, 64, 1024, 2048, 1024, 1024, 4096, 1024};
  int acc_t = 0;
  for (int i = 0; i < 8; i++) {
    ta.src[i] = srcs[i]; ta.dst[i] = dsts[i]; ta.R[i] = Rs[i]; ta.C[i] = Cs[i];
    ta.base[i] = acc_t;
    acc_t += (Rs[i] >> 5) * (Cs[i] >> 5);
  }
  ta.base[8] = acc_t;
  ta.x = x; ta.rmsw = rms1; ta.xn = xn1;
  pre_all<<<acc_t + 4096, dim3(32, 8), 0, stream>>>(ta);

  gemmN<0, 2><<<dim3(32, 16), 256, 0, stream>>>(xn1, 1024, 0, WT_dkv, b_dkv, nullptr, comp, 1024, 1024);

  proj_fused<<<dim3(32, 33), 256, 0, stream>>>(comp,
      WT_qr, b_qr, qr_pre, WT_kr, b_kr, kr_pre,
      WT_kv, b_kv, kvbuf, WT_q, b_q, qbuf);

  rope_vtrans<<<4096 + 1024, 256, 0, stream>>>(qbuf, qr_pre, kvbuf, kr_pre, Qf, kRf, Vf);

  attn_mfma<<<B_ * NH_ * 8, 256, 0, stream>>>(Qf, kvbuf, kRf, Vf, attn_o);

  gemmN<3, 2><<<dim3(32, 16), 256, 0, stream>>>(attn_o, 1024, 0, WT_o, b_o, x, hbuf, 1024, 1024);

  rmsnorm_kernel<<<4096, 256, 0, stream>>>(hbuf, rms2, hn);

  gemmN<2, 4><<<dim3(32, 32), 256, 0, stream>>>(hn, 1024, 0, WT_f1, b_f1, nullptr, hid, 4096, 1024);

  gemm128_splitk<<<dim3(32, 8, 2), 256, 0, stream>>>(hid, 4096, WT_f2, partial, 1024, 4096, 2048);
  f2_reduce<<<4096, 256, 0, stream>>>(partial, hbuf, b_f2, out);
}

// Round 10
// 406.724 us; speedup vs baseline: 1.4356x; 1.0241x over previous
//
#include <hip/hip_runtime.h>

typedef unsigned int u32;
typedef unsigned short u16;
typedef __bf16 bf16x8 __attribute__((ext_vector_type(8)));
typedef float f32x4 __attribute__((ext_vector_type(4)));

#define B_ 4
#define T_ 1024
#define C_ 1024
#define NH_ 16
#define L_ 512
#define DHR_ 64
#define FF_ 4096

typedef __attribute__((address_space(3))) u32 as3_u32;
typedef __attribute__((address_space(1))) u32 as1_u32;

__device__ __forceinline__ void gld16(const u16* g, u16* l) {
  __builtin_amdgcn_global_load_lds((const as1_u32*)g, (as3_u32*)l, 16, 0, 0);
}

__device__ __forceinline__ float bf2f(u16 u) {
  union { u32 i; float f; } v; v.i = ((u32)u) << 16; return v.f;
}
__device__ __forceinline__ u16 f2bf(float f) {
  union { float f; u32 i; } v; v.f = f;
  u32 r = (v.i + 0x7FFFu + ((v.i >> 16) & 1u)) >> 16;
  return (u16)r;
}

// ---------------------------------------------------------------------------
// Fused pre-pass: 8 weight transposes (f32 [R,C] -> bf16 [C,R]) + rmsnorm1
// ---------------------------------------------------------------------------
struct TransArgs {
  const float* src[8];
  u16* dst[8];
  int R[8], C[8];
  int base[9];
  const float* x;
  const float* rmsw;
  u16* xn;
};

__global__ void pre_all(TransArgs ta) {
  const int bid = blockIdx.x;
  if (bid >= ta.base[8]) {  // rmsnorm row
    const int row = bid - ta.base[8];
    const int tid = threadIdx.y * 32 + threadIdx.x;
    const float* xp = ta.x + (size_t)row * C_;
    float v[4];
#pragma unroll
    for (int i = 0; i < 4; i++) v[i] = xp[tid + 256 * i];
    float ss = v[0] * v[0] + v[1] * v[1] + v[2] * v[2] + v[3] * v[3];
#pragma unroll
    for (int o = 32; o > 0; o >>= 1) ss += __shfl_down(ss, o, 64);
    __shared__ float red[4];
    if ((tid & 63) == 0) red[tid >> 6] = ss;
    __syncthreads();
    ss = red[0] + red[1] + red[2] + red[3];
    float scale = rsqrtf(ss * (1.0f / 1024.0f) + 1e-6f);
    u16* op = ta.xn + (size_t)row * C_;
#pragma unroll
    for (int i = 0; i < 4; i++)
      op[tid + 256 * i] = f2bf(v[i] * scale * ta.rmsw[tid + 256 * i]);
    return;
  }
  __shared__ float tile[32][33];
  int w = 0;
#pragma unroll
  for (int i = 1; i < 8; i++) w += (bid >= ta.base[i]);
  const int local = bid - ta.base[w];
  const int R = ta.R[w], C = ta.C[w];
  const int ctiles = C >> 5;
  const int bx = (local % ctiles) * 32;
  const int by = (local / ctiles) * 32;
  const float* in = ta.src[w];
  u16* outp = ta.dst[w];
  const int tx = threadIdx.x, ty = threadIdx.y;
  for (int i = ty; i < 32; i += 8)
    tile[i][tx] = in[(size_t)(by + i) * C + bx + tx];
  __syncthreads();
  for (int i = ty; i < 32; i += 8)
    outp[(size_t)(bx + i) * R + by + tx] = f2bf(tile[tx][i]);
}

// ---------------------------------------------------------------------------
// RMSNorm (standalone, for h)
// ---------------------------------------------------------------------------
__global__ __launch_bounds__(256) void rmsnorm_kernel(const float* __restrict__ xin,
                                                      const float* __restrict__ w,
                                                      u16* __restrict__ outp) {
  const int row = blockIdx.x;
  const int tid = threadIdx.x;
  const float* xp = xin + (size_t)row * C_;
  float v[4];
#pragma unroll
  for (int i = 0; i < 4; i++) v[i] = xp[tid + 256 * i];
  float ss = v[0] * v[0] + v[1] * v[1] + v[2] * v[2] + v[3] * v[3];
#pragma unroll
  for (int o = 32; o > 0; o >>= 1) ss += __shfl_down(ss, o, 64);
  __shared__ float red[4];
  if ((tid & 63) == 0) red[tid >> 6] = ss;
  __syncthreads();
  ss = red[0] + red[1] + red[2] + red[3];
  float scale = rsqrtf(ss * (1.0f / 1024.0f) + 1e-6f);
  u16* op = outp + (size_t)row * C_;
#pragma unroll
  for (int i = 0; i < 4; i++)
    op[tid + 256 * i] = f2bf(v[i] * scale * w[tid + 256 * i]);
}

// ---------------------------------------------------------------------------
// MFMA GEMM body, BK=64 with XOR-swizzled global_load_lds staging.
// ---------------------------------------------------------------------------
template<int EPI, bool NCLIP, int NT>
__device__ __forceinline__ void g_body(
    u16* As, u16* Bs,
    const u16* __restrict__ A, int lda, int aoff,
    const u16* __restrict__ BT, const float* __restrict__ bias,
    const float* __restrict__ resid, void* __restrict__ out,
    int N, int Kfull, int Klen, int m0, int n0, int koff) {
  const int tid = threadIdx.x;
  const int wave = tid >> 6, lane = tid & 63;
  const int wm = wave >> 1, wn = wave & 1;
  const int quad = lane >> 4, l15 = lane & 15;
  const int srow = tid >> 3;
  const int gseg = (tid & 7) ^ (srow & 7);

  const u16* aP = A + (size_t)(m0 + srow) * lda + aoff + koff + gseg * 8;
  const u16* bP = BT + (size_t)(n0 + srow) * Kfull + koff + gseg * 8;
  u16* aL = As + tid * 8;
  u16* bL = Bs + tid * 8;
  const size_t aStep = (size_t)32 * lda;
  const size_t bStep = (size_t)32 * Kfull;

  f32x4 acc[4][NT] = {};

  for (int k0 = 0; k0 < Klen; k0 += 64) {
#pragma unroll
    for (int c = 0; c < 4; c++)
      gld16(aP + k0 + c * aStep, aL + c * 32 * 64);
#pragma unroll
    for (int c = 0; c < NT; c++)
      gld16(bP + k0 + c * bStep, bL + c * 32 * 64);
    __syncthreads();
#pragma unroll
    for (int kh = 0; kh < 2; kh++) {
      bf16x8 af[4], bfr[NT];
#pragma unroll
      for (int mt = 0; mt < 4; mt++) {
        const int r = wm * 64 + mt * 16 + l15;
        const int p = (kh * 4 + quad) ^ (r & 7);
        af[mt] = *(const bf16x8*)&As[r * 64 + p * 8];
      }
#pragma unroll
      for (int nt = 0; nt < NT; nt++) {
        const int r = wn * (NT * 16) + nt * 16 + l15;
        const int p = (kh * 4 + quad) ^ (r & 7);
        bfr[nt] = *(const bf16x8*)&Bs[r * 64 + p * 8];
      }
#pragma unroll
      for (int mt = 0; mt < 4; mt++)
#pragma unroll
        for (int nt = 0; nt < NT; nt++)
          acc[mt][nt] = __builtin_amdgcn_mfma_f32_16x16x32_bf16(af[mt], bfr[nt], acc[mt][nt], 0, 0, 0);
    }
    __syncthreads();
  }

  float bvv[NT];
#pragma unroll
  for (int nt = 0; nt < NT; nt++) {
    const int gn = n0 + wn * (NT * 16) + nt * 16 + l15;
    bvv[nt] = (EPI == 4) ? 0.0f : ((NCLIP && gn >= N) ? 0.0f : bias[gn]);
  }
#pragma unroll
  for (int mt = 0; mt < 4; mt++) {
#pragma unroll
    for (int i = 0; i < 4; i++) {
      const int gm = m0 + wm * 64 + mt * 16 + quad * 4 + i;
      const size_t rowb = (size_t)gm * N;
#pragma unroll
      for (int nt = 0; nt < NT; nt++) {
        const int gn = n0 + wn * (NT * 16) + nt * 16 + l15;
        if (NCLIP && gn >= N) continue;
        const size_t oidx = rowb + gn;
        float v = acc[mt][nt][i] + bvv[nt];
        if (EPI == 2) {  // fast tanh-gelu: x*t/(t+1), t=e^{2y}
          float y = 0.7978845608028654f * (v + 0.044715f * v * v * v);
          float t = __expf(fminf(2.0f * y, 80.0f));
          v = v * t / (t + 1.0f);
        }
        if (EPI == 3) v += resid[oidx];
        if (EPI == 1 || EPI == 3 || EPI == 4) ((float*)out)[oidx] = v;
        else ((u16*)out)[oidx] = f2bf(v);
      }
    }
  }
}

template<int EPI, int NT>
__global__ __launch_bounds__(256) void gemmN(
    const u16* __restrict__ A, int lda, int aoff,
    const u16* __restrict__ BT, const float* __restrict__ bias,
    const float* __restrict__ resid, void* __restrict__ out,
    int N, int K) {
  __shared__ __align__(16) u16 As[128 * 64];
  __shared__ __align__(16) u16 Bs[NT * 32 * 64];
  g_body<EPI, false, NT>(As, Bs, A, lda, aoff, BT, bias, resid, out,
                         N, K, K, blockIdx.x * 128, blockIdx.y * (NT * 32), 0);
}

// split-K (blockIdx.z = K chunk) -> f32 partials, no bias
__global__ __launch_bounds__(256) void gemm128_splitk(
    const u16* __restrict__ A, int lda, const u16* __restrict__ BT,
    float* __restrict__ part, int N, int Kfull, int Klen) {
  __shared__ __align__(16) u16 As[128 * 64];
  __shared__ __align__(16) u16 Bs[128 * 64];
  const int z = blockIdx.z;
  g_body<4, false, 4>(As, Bs, A, lda, 0, BT, nullptr, nullptr,
                      part + (size_t)z * 4096 * N,
                      N, Kfull, Klen, blockIdx.x * 128, blockIdx.y * 128, z * Klen);
}

// out = h + bias + part[0..1]   (split-K=2)
__global__ __launch_bounds__(256) void f2_reduce(
    const float* __restrict__ part, const float* __restrict__ h,
    const float* __restrict__ bias, float* __restrict__ out) {
  const size_t base = (size_t)blockIdx.x * 1024;
  const size_t PS = (size_t)4096 * 1024;
#pragma unroll
  for (int i = 0; i < 4; i++) {
    const int col = threadIdx.x + 256 * i;
    out[base + col] = h[base + col] + bias[col] + part[base + col] +
                      part[PS + base + col];
  }
}

// ---------------------------------------------------------------------------
// Fused qr/kr/kv/q projections, all reading comp. grid (32, 33).
// ---------------------------------------------------------------------------
__global__ __launch_bounds__(256) void proj_fused(
    const u16* __restrict__ comp,
    const u16* __restrict__ WT_qr, const float* __restrict__ b_qr, float* __restrict__ qr_pre,
    const u16* __restrict__ WT_kr, const float* __restrict__ b_kr, float* __restrict__ kr_pre,
    const u16* __restrict__ WT_kv, const float* __restrict__ b_kv, u16* __restrict__ kvbuf,
    const u16* __restrict__ WT_q, const float* __restrict__ b_q, u16* __restrict__ qbuf) {
  __shared__ __align__(16) u16 As[128 * 64];
  __shared__ __align__(16) u16 Bs[128 * 64];
  const int m0 = blockIdx.x * 128;
  const int ny = blockIdx.y;
  if (ny < 8)
    g_body<1, false, 4>(As, Bs, comp, 1024, 0, WT_qr, b_qr, nullptr, qr_pre, 1024, 1024, 1024, m0, ny * 128, 0);
  else if (ny == 8)
    g_body<1, true, 4>(As, Bs, comp, 1024, 0, WT_kr, b_kr, nullptr, kr_pre, 64, 1024, 1024, m0, 0, 0);
  else if (ny < 25)
    g_body<0, false, 4>(As, Bs, comp, 1024, 0, WT_kv, b_kv, nullptr, kvbuf, 2048, 512, 512, m0, (ny - 9) * 128, 0);
  else
    g_body<0, false, 4>(As, Bs, comp, 1024, 512, WT_q, b_q, nullptr, qbuf, 1024, 512, 512, m0, (ny - 25) * 128, 0);
}

// ---------------------------------------------------------------------------
// Fused RoPE head-assembly (blocks 0..4095) + V transpose (blocks 4096..5119)
// ---------------------------------------------------------------------------
__global__ __launch_bounds__(256) void rope_vtrans(
    const u16* __restrict__ qb, const float* __restrict__ qr_pre,
    const u16* __restrict__ kvb, const float* __restrict__ kr_pre,
    u16* __restrict__ Qf, u16* __restrict__ kRf, u16* __restrict__ Vf) {
  __shared__ u16 tile[64][72];
  if (blockIdx.x >= 4096) {  // vtrans
    const int bid2 = blockIdx.x - 4096;
    const int bh = bid2 & 63, t0 = (bid2 >> 6) * 64;
    const int b = bh >> 4, h = bh & 15;
    const int r = threadIdx.x >> 2, seg = (threadIdx.x & 3) * 16;
    const u16* src = &kvb[((size_t)(b * 1024) + t0 + r) * 2048 + 1024 + h * 64 + seg];
    *(uint4*)&tile[r][seg] = *(const uint4*)src;
    *(uint4*)&tile[r][seg + 8] = *(const uint4*)(src + 8);
    __syncthreads();
    const int d = threadIdx.x >> 2, ts = (threadIdx.x & 3) * 16;
    u16 tmp[16];
#pragma unroll
    for (int j = 0; j < 16; j++) tmp[j] = tile[ts + j][d];
    u16* dst = &Vf[((size_t)bh * 64 + d) * 1024 + t0 + ts];
    *(uint4*)dst = *(uint4*)tmp;
    *(uint4*)(dst + 8) = *(uint4*)(tmp + 8);
    return;
  }
  const int bt = blockIdx.x;
  const int b = bt >> 10, t = bt & 1023;
  const float freq = (float)(t + 1);
  for (int idx = threadIdx.x; idx < 2048; idx += 256) {
    const int h = idx >> 7, d = idx & 127;
    const size_t dst = (((size_t)(b * 16 + h)) * T_ + t) * 128 + d;
    if (d < 64) {
      Qf[dst] = qb[(size_t)bt * C_ + h * 64 + d];
    } else {
      const int dd = d - 64;
      const int g = h * 64 + dd;
      const int p = g >> 1;
      const float theta = __expf(-(float)(2 * p) * (9.210340372f / 1024.0f));
      float s, c;
      sincosf(freq * theta, &s, &c);
      const float x0 = qr_pre[(size_t)bt * 1024 + (p << 1)];
      const float x1 = qr_pre[(size_t)bt * 1024 + (p << 1) + 1];
      Qf[dst] = f2bf((g & 1) ? (x1 * c + x0 * s) : (x0 * c - x1 * s));
      if (h == 0) {  // kR is head-independent: write once
        const int p2 = dd >> 1;
        const float theta2 = __expf(-(float)(2 * p2) * (9.210340372f / 64.0f));
        float s2, c2;
        sincosf(freq * theta2, &s2, &c2);
        const float y0 = kr_pre[(size_t)bt * 64 + (p2 << 1)];
        const float y1 = kr_pre[(size_t)bt * 64 + (p2 << 1) + 1];
        kRf[(size_t)bt * 64 + dd] = f2bf((dd & 1) ? (y1 * c2 + y0 * s2) : (y0 * c2 - y1 * s2));
      }
    }
  }
}

// ---------------------------------------------------------------------------
// MFMA flash attention v4: ONE q-tile per block (1024 blocks = 4/CU),
// heavy tiles first, register-prefetch double buffering of K/V staging.
// K staged from kvbuf (head slice) + kRf (shared RoPE part).
// XCD-local decode: bh in low 6 bits.
// ---------------------------------------------------------------------------
#define KSTR 136
#define VSTR 72

__global__ __launch_bounds__(256, 4) void attn_mfma(
    const u16* __restrict__ Qf, const u16* __restrict__ kvbuf,
    const u16* __restrict__ kRf, const u16* __restrict__ Vf,
    u16* __restrict__ attn_o) {
  __shared__ __align__(16) u16 Ks[64 * KSTR];
  __shared__ __align__(16) u16 Vt[64 * VSTR];
  __shared__ __align__(16) u16 Ps[4 * 16 * VSTR];

  const int bh_lin = blockIdx.x & 63;
  const int j = blockIdx.x >> 6;       // 0..15, j=0 -> heaviest tile
  const int h = bh_lin & 15;
  const int b = bh_lin >> 4;
  const int qt = 15 - j;
  const int q0 = qt * 64;
  const size_t bh = (size_t)(b * 16 + h);

  const int tid = threadIdx.x;
  const int wave = tid >> 6, lane = tid & 63;
  const int quad = lane >> 4, l15 = lane & 15;

  bf16x8 qfrag[4];
  {
    const u16* qb = &Qf[(bh * T_ + q0 + wave * 16 + l15) * 128 + quad * 8];
#pragma unroll
    for (int kc = 0; kc < 4; kc++) qfrag[kc] = *(const bf16x8*)(qb + kc * 32);
  }

  f32x4 acc_o[4] = {};
  float m_i[4], l_i[4];
#pragma unroll
  for (int i = 0; i < 4; i++) { m_i[i] = -3.0e38f; l_i[i] = 0.0f; }

  const int kr_ = tid >> 3, kcs = (tid & 7) * 16;
  const int vd = tid >> 2, vts = (tid & 3) * 16;
  u16* Pw = Ps + wave * 16 * VSTR;

  const bool isk = kcs < 64;
  const size_t rstep = isk ? (size_t)32 * 2048 : (size_t)32 * 64;

  // register prefetch buffers (double-buffer the staging)
  uint4 kA0, kA1, kB0, kB1, vr0, vr1;
  auto prefetch = [&](int kt) {
    const int t_row = kt * 64 + kr_;
    const u16* s0 = isk
        ? &kvbuf[((size_t)(b * T_) + t_row) * 2048 + h * 64 + kcs]
        : &kRf[((size_t)(b * T_) + t_row) * 64 + (kcs - 64)];
    const u16* s1 = s0 + rstep;
    kA0 = *(const uint4*)s0; kA1 = *(const uint4*)(s0 + 8);
    kB0 = *(const uint4*)s1; kB1 = *(const uint4*)(s1 + 8);
    const u16* vs = &Vf[(bh * 64 + vd) * 1024 + kt * 64 + vts];
    vr0 = *(const uint4*)vs; vr1 = *(const uint4*)(vs + 8);
  };
  prefetch(0);

  for (int kt = 0; kt <= qt; kt++) {
    __syncthreads();  // prior iteration's LDS readers done
    *(uint4*)&Ks[kr_ * KSTR + kcs] = kA0;
    *(uint4*)&Ks[kr_ * KSTR + kcs + 8] = kA1;
    *(uint4*)&Ks[(kr_ + 32) * KSTR + kcs] = kB0;
    *(uint4*)&Ks[(kr_ + 32) * KSTR + kcs + 8] = kB1;
    *(uint4*)&Vt[vd * VSTR + vts] = vr0;
    *(uint4*)&Vt[vd * VSTR + vts + 8] = vr1;
    __syncthreads();
    if (kt < qt) prefetch(kt + 1);  // overlaps with compute below

    f32x4 acc_s[4] = {};
#pragma unroll
    for (int kc = 0; kc < 4; kc++) {
#pragma unroll
      for (int ng = 0; ng < 4; ng++) {
        bf16x8 bb = *(const bf16x8*)&Ks[(ng * 16 + l15) * KSTR + kc * 32 + quad * 8];
        acc_s[ng] = __builtin_amdgcn_mfma_f32_16x16x32_bf16(qfrag[kc], bb, acc_s[ng], 0, 0, 0);
      }
    }

    float sv[4][4];
#pragma unroll
    for (int ng = 0; ng < 4; ng++)
#pragma unroll
      for (int i = 0; i < 4; i++) {
        float s = acc_s[ng][i] * 0.125f;
        if (kt == qt && (ng * 16 + l15) > (wave * 16 + quad * 4 + i)) s = -3.0e38f;
        sv[ng][i] = s;
      }

    float alpha[4], mx[4];
#pragma unroll
    for (int i = 0; i < 4; i++) {
      float m = fmaxf(fmaxf(sv[0][i], sv[1][i]), fmaxf(sv[2][i], sv[3][i]));
#pragma unroll
      for (int off = 1; off < 16; off <<= 1) m = fmaxf(m, __shfl_xor(m, off, 64));
      float mn = fmaxf(m_i[i], m);
      alpha[i] = __expf(m_i[i] - mn);
      m_i[i] = mn;
      mx[i] = mn;
    }
    float rs[4] = {0.f, 0.f, 0.f, 0.f};
#pragma unroll
    for (int ng = 0; ng < 4; ng++)
#pragma unroll
      for (int i = 0; i < 4; i++) {
        float p = __expf(sv[ng][i] - mx[i]);
        rs[i] += p;
        Pw[(quad * 4 + i) * VSTR + ng * 16 + l15] = f2bf(p);
      }
#pragma unroll
    for (int i = 0; i < 4; i++) {
      float r = rs[i];
#pragma unroll
      for (int off = 1; off < 16; off <<= 1) r += __shfl_xor(r, off, 64);
      l_i[i] = l_i[i] * alpha[i] + r;
    }

#pragma unroll
    for (int ng = 0; ng < 4; ng++)
#pragma unroll
      for (int i = 0; i < 4; i++) acc_o[ng][i] *= alpha[i];
#pragma unroll
    for (int kc = 0; kc < 2; kc++) {
      bf16x8 a = *(const bf16x8*)&Pw[l15 * VSTR + kc * 32 + quad * 8];
#pragma unroll
      for (int ng = 0; ng < 4; ng++) {
        bf16x8 bb = *(const bf16x8*)&Vt[(ng * 16 + l15) * VSTR + kc * 32 + quad * 8];
        acc_o[ng] = __builtin_amdgcn_mfma_f32_16x16x32_bf16(a, bb, acc_o[ng], 0, 0, 0);
      }
    }
  }

  float linv[4];
#pragma unroll
  for (int i = 0; i < 4; i++) linv[i] = 1.0f / l_i[i];
#pragma unroll
  for (int ng = 0; ng < 4; ng++)
#pragma unroll
    for (int i = 0; i < 4; i++) {
      const int qrow = q0 + wave * 16 + quad * 4 + i;
      attn_o[((size_t)(b * T_) + qrow) * C_ + h * 64 + ng * 16 + l15] =
          f2bf(acc_o[ng][i] * linv[i]);
    }
}

// ---------------------------------------------------------------------------
extern "C" void kernel_launch(void* const* d_in, const int* in_sizes, int n_in,
                              void* d_out, int out_size, void* d_ws, size_t ws_size,
                              hipStream_t stream) {
  const float* x = (const float*)d_in[0];
  const float* rms1 = (const float*)d_in[1];
  const float* rms2 = (const float*)d_in[2];
  const float* W_dkv = (const float*)d_in[3];
  const float* b_dkv = (const float*)d_in[4];
  const float* W_kr = (const float*)d_in[5];
  const float* b_kr = (const float*)d_in[6];
  const float* W_qr = (const float*)d_in[7];
  const float* b_qr = (const float*)d_in[8];
  const float* W_kv = (const float*)d_in[9];
  const float* b_kv = (const float*)d_in[10];
  const float* W_q = (const float*)d_in[11];
  const float* b_q = (const float*)d_in[12];
  const float* W_o = (const float*)d_in[13];
  const float* b_o = (const float*)d_in[14];
  const float* W_f1 = (const float*)d_in[15];
  const float* b_f1 = (const float*)d_in[16];
  const float* W_f2 = (const float*)d_in[17];
  const float* b_f2 = (const float*)d_in[18];
  float* out = (float*)d_out;

  char* ws = (char*)d_ws;
  size_t off = 0;
  auto alloc = [&](size_t bytes) -> void* {
    void* p = ws + off;
    off += (bytes + 255) & ~(size_t)255;
    return p;
  };
  u16* WT_dkv = (u16*)alloc((size_t)1024 * 1024 * 2);
  u16* WT_kr  = (u16*)alloc((size_t)128 * 1024 * 2);
  u16* WT_qr  = (u16*)alloc((size_t)1024 * 1024 * 2);
  u16* WT_kv  = (u16*)alloc((size_t)2048 * 512 * 2);
  u16* WT_q   = (u16*)alloc((size_t)1024 * 512 * 2);
  u16* WT_o   = (u16*)alloc((size_t)1024 * 1024 * 2);
  u16* WT_f1  = (u16*)alloc((size_t)4096 * 1024 * 2);
  u16* WT_f2  = (u16*)alloc((size_t)1024 * 4096 * 2);
  u16* xn1    = (u16*)alloc((size_t)4096 * 1024 * 2);
  u16* comp   = (u16*)alloc((size_t)4096 * 1024 * 2);
  float* kr_pre = (float*)alloc((size_t)4096 * 64 * 4);
  float* qr_pre = (float*)alloc((size_t)4096 * 1024 * 4);
  u16* kvbuf  = (u16*)alloc((size_t)4096 * 2048 * 2);
  u16* qbuf   = (u16*)alloc((size_t)4096 * 1024 * 2);
  // Qf..attn_o form a contiguous ~32.5 MB region reused as f2 partials
  u16* Qf     = (u16*)alloc((size_t)64 * 1024 * 128 * 2);   // 16 MB
  u16* kRf    = (u16*)alloc((size_t)4096 * 64 * 2);         // 0.5 MB
  u16* Vf     = (u16*)alloc((size_t)64 * 64 * 1024 * 2);    // 8 MB
  u16* attn_o = (u16*)alloc((size_t)4096 * 1024 * 2);       // 8 MB
  float* hbuf = (float*)alloc((size_t)4096 * 1024 * 4);
  u16* hn     = (u16*)alloc((size_t)4096 * 1024 * 2);
  u16* hid    = (u16*)alloc((size_t)4096 * 4096 * 2);
  float* partial = (float*)Qf;  // 2 x 16 MB over Qf..attn_o, dead by f2 time

  TransArgs ta;
  const float* srcs[8] = {W_dkv, W_kr, W_qr, W_kv, W_q, W_o, W_f1, W_f2};
  u16* dsts[8] = {WT_dkv, WT_kr, WT_qr, WT_kv, WT_q, WT_o, WT_f1, WT_f2};
  const int Rs[8] = {1024, 1024, 1024, 512, 512, 1024, 1024, 4096};
  const int Cs[8] = {1024, 64, 1024, 2048, 1024, 1024, 4096, 1024};
  int acc_t = 0;
  for (int i = 0; i < 8; i++) {
    ta.src[i] = srcs[i]; ta.dst[i] = dsts[i]; ta.R[i] = Rs[i]; ta.C[i] = Cs[i];
    ta.base[i] = acc_t;
    acc_t += (Rs[i] >> 5) * (Cs[i] >> 5);
  }
  ta.base[8] = acc_t;
  ta.x = x; ta.rmsw = rms1; ta.xn = xn1;
  pre_all<<<acc_t + 4096, dim3(32, 8), 0, stream>>>(ta);

  gemmN<0, 2><<<dim3(32, 16), 256, 0, stream>>>(xn1, 1024, 0, WT_dkv, b_dkv, nullptr, comp, 1024, 1024);

  proj_fused<<<dim3(32, 33), 256, 0, stream>>>(comp,
      WT_qr, b_qr, qr_pre, WT_kr, b_kr, kr_pre,
      WT_kv, b_kv, kvbuf, WT_q, b_q, qbuf);

  rope_vtrans<<<4096 + 1024, 256, 0, stream>>>(qbuf, qr_pre, kvbuf, kr_pre, Qf, kRf, Vf);

  attn_mfma<<<B_ * NH_ * 16, 256, 0, stream>>>(Qf, kvbuf, kRf, Vf, attn_o);

  gemmN<3, 2><<<dim3(32, 16), 256, 0, stream>>>(attn_o, 1024, 0, WT_o, b_o, x, hbuf, 1024, 1024);

  rmsnorm_kernel<<<4096, 256, 0, stream>>>(hbuf, rms2, hn);

  gemmN<2, 4><<<dim3(32, 32), 256, 0, stream>>>(hn, 1024, 0, WT_f1, b_f1, nullptr, hid, 4096, 1024);

  gemm128_splitk<<<dim3(32, 8, 2), 256, 0, stream>>>(hid, 4096, WT_f2, partial, 1024, 4096, 2048);
  f2_reduce<<<4096, 256, 0, stream>>>(partial, hbuf, b_f2, out);
}